// Round 19
// baseline (708.465 us; speedup 1.0000x reference)
//
#include <hip/hip_runtime.h>
#include <cstdint>
#include <cstddef>

// ---------------------------------------------------------------------------
// GatedDeltaNet forward, MI355X/gfx950.
// R19 = R18 + qknorm_kernel: k AND q normalized ONCE per (b,hq,chunk), written
// IN PLACE into QKV (race-free: each thread reads exactly what it writes) plus
// KNT transpose. seq's q math deleted (pure bitcast frag load); intra's k/q
// staging become copies. No new workspace.
// ---------------------------------------------------------------------------

#define ROWS  4096
#define SEQ   2048
#define HIDN  2048
#define NWP   12288     // logical N of GEMM1 (48 tiles)
#define NUMV  32

#define LDH   2080      // hsb row stride (elems)
#define LDW   2080      // WT row stride
#define LDWO  4160      // WoT row stride
#define LDC1  12416     // C1 / WU row stride
#define LDQ   8256      // QKV row stride
#define LDCO  4160      // CORE / NRM row stride

using bf16x8 = __attribute__((ext_vector_type(8))) short;
using f32x4v = __attribute__((ext_vector_type(4))) float;

__device__ __forceinline__ float bf2f(unsigned short u) {
  union { unsigned int i; float f; } x; x.i = ((unsigned int)u) << 16; return x.f;
}
__device__ __forceinline__ unsigned short f2bf(float f) {
  union { float f; unsigned int u; } x; x.f = f;
  unsigned int u = x.u;
  unsigned int r = (u + 0x7FFFu + ((u >> 16) & 1u)) >> 16;  // RNE
  return (unsigned short)r;
}

typedef const __attribute__((address_space(1))) unsigned int GU32;
typedef __attribute__((address_space(3))) unsigned int LU32;
__device__ __forceinline__ void gld_lds16(const void* g, void* l) {
  GU32* gp = (GU32*)(unsigned long long)(uintptr_t)g;
  LU32* lp = (LU32*)(unsigned int)(uintptr_t)l;  // flat-LDS low32 = LDS offset
  __builtin_amdgcn_global_load_lds(gp, lp, 16, 0, 0);
}
template <int N>
__device__ __forceinline__ void waitcnt_vm() {
  asm volatile("s_waitcnt vmcnt(%0)" ::"i"(N) : "memory");
}

// ---------------------------------------------------------------- cast fp32->bf16 (ld-padded)
__global__ __launch_bounds__(256) void cast_kernel(const float* __restrict__ in,
                                                   unsigned short* __restrict__ out) {
  int i = blockIdx.x * 256 + threadIdx.x;   // ROWS * 256
  int row = i >> 8;
  int c8 = (i & 255) * 8;
  float4 v0 = *(const float4*)(in + (size_t)row * 2048 + c8);
  float4 v1 = *(const float4*)(in + (size_t)row * 2048 + c8 + 4);
  unsigned short o[8];
  o[0] = f2bf(v0.x); o[1] = f2bf(v0.y); o[2] = f2bf(v0.z); o[3] = f2bf(v0.w);
  o[4] = f2bf(v1.x); o[5] = f2bf(v1.y); o[6] = f2bf(v1.z); o[7] = f2bf(v1.w);
  *(uint4*)(out + (size_t)row * LDH + c8) = *(const uint4*)o;
}

// ------------------------------------------------- transpose W[K][N] -> WT[roff+N][K] (ld)
__global__ __launch_bounds__(256) void transpose_kernel(const float* __restrict__ W,
                                                        unsigned short* __restrict__ WT,
                                                        int K, int N, int ld, int roff) {
  __shared__ float tile[64][65];
  const int t = threadIdx.x;
  const int kb = blockIdx.y * 64, nb = blockIdx.x * 64;
  const int r = t >> 2, c0 = (t & 3) * 16;
#pragma unroll
  for (int i = 0; i < 16; ++i) {
    int c = c0 + i;
    float v = 0.f;
    if (nb + c < N) v = W[(size_t)(kb + r) * N + nb + c];
    tile[r][c] = v;
  }
  __syncthreads();
  const int bn = t >> 2, seg = (t & 3) * 16;
  if (nb + bn < N) {
    unsigned short tmp[16];
#pragma unroll
    for (int i = 0; i < 16; ++i) tmp[i] = f2bf(tile[seg + i][bn]);
    unsigned short* dst = WT + (size_t)(roff + nb + bn) * ld + kb + seg;
    *(uint4*)dst = *(const uint4*)&tmp[0];
    *(uint4*)(dst + 8) = *(const uint4*)&tmp[8];
  }
}

// ---------------------------------------------------------------- WbaK[k][c] = [W_b | W_a] bf16
__global__ __launch_bounds__(256) void bacat_kernel(const float* __restrict__ Wb,
                                                    const float* __restrict__ Wa,
                                                    unsigned short* __restrict__ WbaK) {
  int idx = blockIdx.x * 256 + threadIdx.x;   // 2048*64
  int k = idx >> 6, c = idx & 63;
  float v = (c < 32) ? Wb[k * 32 + c] : Wa[k * 32 + (c - 32)];
  WbaK[idx] = f2bf(v);
}

// ---------------------------------------------------------------- b/a projections -> beta/g
__global__ __launch_bounds__(256) void ba_kernel(const unsigned short* __restrict__ hsb,
                                                 const unsigned short* __restrict__ WbaK,
                                                 const float* __restrict__ dt_bias,
                                                 const float* __restrict__ A_log,
                                                 float* __restrict__ G, float* __restrict__ BETA) {
  __shared__ unsigned short hsl[8][2048];   // 32 KB
  __shared__ float pacc[4][8][64];          // 8 KB
  const int t = threadIdx.x;
  const int lane = t & 63, w = t >> 6;
  const int row0 = blockIdx.x * 8;
#pragma unroll
  for (int rr = 0; rr < 2; ++rr) {
    const int r = w * 2 + rr;
    const unsigned short* src = hsb + (size_t)(row0 + r) * LDH + lane * 32;
#pragma unroll
    for (int j = 0; j < 8; ++j)
      *(ushort4*)&hsl[r][lane * 32 + j * 4] = *(const ushort4*)(src + j * 4);
  }
  __syncthreads();
  float acc[8] = {0.f, 0.f, 0.f, 0.f, 0.f, 0.f, 0.f, 0.f};
  const int kb0 = w * 512;
#pragma unroll 1
  for (int k = 0; k < 512; k += 4) {
    const unsigned short* wp = WbaK + (size_t)(kb0 + k) * 64 + lane;
    const float w0 = bf2f(wp[0]);
    const float w1 = bf2f(wp[64]);
    const float w2 = bf2f(wp[128]);
    const float w3 = bf2f(wp[192]);
#pragma unroll
    for (int r = 0; r < 8; ++r) {
      ushort4 hv = *(const ushort4*)&hsl[r][kb0 + k];
      acc[r] += bf2f(hv.x) * w0 + bf2f(hv.y) * w1 + bf2f(hv.z) * w2 + bf2f(hv.w) * w3;
    }
  }
#pragma unroll
  for (int r = 0; r < 8; ++r) pacc[w][r][lane] = acc[r];
  __syncthreads();
  const int r = t >> 5, hc = t & 31;
  float bp = pacc[0][r][hc] + pacc[1][r][hc] + pacc[2][r][hc] + pacc[3][r][hc];
  float ap = pacc[0][r][32 + hc] + pacc[1][r][32 + hc] + pacc[2][r][32 + hc] + pacc[3][r][32 + hc];
  const int idx = (row0 + r) * NUMV + hc;
  BETA[idx] = 1.f / (1.f + __expf(-bp));
  float x = ap + dt_bias[hc];
  float sp = (x > 15.f) ? x : log1pf(__expf(x));
  G[idx] = -__expf(A_log[hc]) * sp;
}

// ---------------------------------------------------------------- q/k norm -> in place + KNT
// grid 1024 = b(2) x hq(16) x chunk(32). Normalizes k and q ONCE per (b,hq,row),
// writes back in place into QKV (each thread writes only what it read) and also
// stores k transposed to KNT[d][i] bf16. q additionally scaled by DK^-0.5.
__global__ __launch_bounds__(256) void qknorm_kernel(unsigned short* __restrict__ QKV,
                                                     unsigned short* __restrict__ KNT) {
  const int t = threadIdx.x;
  const int chunk = blockIdx.x & 31;
  const int hq = (blockIdx.x >> 5) & 15;
  const int b = blockIdx.x >> 9;
  const int row0 = chunk * 64;
  const int r = t >> 2, q4 = t & 3;
  const size_t grow = ((size_t)b * SEQ + row0 + r) * (size_t)LDQ;
  // ---- k ----
  {
    unsigned short* kp = QKV + grow + 2048 + hq * 128 + q4 * 32;
    float kv[32]; float ssk = 0.f;
#pragma unroll
    for (int j = 0; j < 32; j += 4) {
      ushort4 km = *(const ushort4*)(kp + j);
      kv[j] = bf2f(km.x); kv[j + 1] = bf2f(km.y); kv[j + 2] = bf2f(km.z); kv[j + 3] = bf2f(km.w);
      ssk += kv[j]*kv[j] + kv[j+1]*kv[j+1] + kv[j+2]*kv[j+2] + kv[j+3]*kv[j+3];
    }
    ssk += __shfl_xor(ssk, 1, 64);
    ssk += __shfl_xor(ssk, 2, 64);
    const float rk = rsqrtf(ssk + 1e-6f);
    unsigned short knb[32];
#pragma unroll
    for (int j = 0; j < 32; ++j) knb[j] = f2bf(kv[j] * rk);
    unsigned short* kb = KNT + ((((size_t)b * 16 + hq) * 32 + chunk) << 13) + (size_t)(q4 * 32) * 64 + r;
#pragma unroll
    for (int j = 0; j < 32; ++j) kb[(size_t)j * 64] = knb[j];
#pragma unroll
    for (int j = 0; j < 32; j += 8) {
      *(uint4*)(kp + j) = *(const uint4*)&knb[j];
    }
  }
  // ---- q ----
  {
    unsigned short* qp = QKV + grow + hq * 128 + q4 * 32;
    float qv[32]; float ssq = 0.f;
#pragma unroll
    for (int j = 0; j < 32; j += 4) {
      ushort4 qm = *(const ushort4*)(qp + j);
      qv[j] = bf2f(qm.x); qv[j + 1] = bf2f(qm.y); qv[j + 2] = bf2f(qm.z); qv[j + 3] = bf2f(qm.w);
      ssq += qv[j]*qv[j] + qv[j+1]*qv[j+1] + qv[j+2]*qv[j+2] + qv[j+3]*qv[j+3];
    }
    ssq += __shfl_xor(ssq, 1, 64);
    ssq += __shfl_xor(ssq, 2, 64);
    const float rq = rsqrtf(ssq + 1e-6f) * 0.08838834764831845f;  // * DK^-0.5
    unsigned short qnb[32];
#pragma unroll
    for (int j = 0; j < 32; ++j) qnb[j] = f2bf(qv[j] * rq);
#pragma unroll
    for (int j = 0; j < 32; j += 8) {
      *(uint4*)(qp + j) = *(const uint4*)&qnb[j];
    }
  }
}

// ---------------------------------------------------------------- ring-5 pair-barrier GEMM
template <int BM, int BN, int OUT_BF16>
__global__ __launch_bounds__(512) void gemm_r5_kernel(const unsigned short* __restrict__ Ag,
                                                      const unsigned short* __restrict__ Bg,
                                                      void* __restrict__ Cg, int M, int N, int K,
                                                      int lda, int ldb, int ldc) {
  constexpr int PM = BM / 2, PN = BN / 4;
  constexpr int MT = PM / 16, NTF = PN / 16;
  constexpr int NA = BM / 128, NB = BN / 128;
  constexpr int LPS = NA + NB;
  constexpr int REG = (BM + BN) * 64;
  extern __shared__ char lds[];
  const int t = threadIdx.x;
  const int lane = t & 63, wid = t >> 6;
  const int wm = wid >> 2, wn = wid & 3;
  const int rlo = lane & 15, khi = lane >> 4;

  const int gx = gridDim.x, nwg = gx * gridDim.y;
  int id = blockIdx.y * gx + blockIdx.x;
  int sid = (id & 7) * (nwg >> 3) + (id >> 3);
  const int m0 = (sid / gx) * BM, n0 = (sid % gx) * BN;

  const int NT = K >> 6;
  const int NPH = NT * 2;

  const int srow = t >> 2;
  const int scs = ((t & 3) * 16) ^ (((t >> 3) & 3) << 4);
  const char* Ap[NA];
  const char* Bp[NB];
#pragma unroll
  for (int i = 0; i < NA; ++i)
    Ap[i] = (const char*)Ag + (size_t)(m0 + i * 128 + srow) * lda * 2 + scs;
#pragma unroll
  for (int i = 0; i < NB; ++i)
    Bp[i] = (const char*)Bg + (size_t)(n0 + i * 128 + srow) * ldb * 2 + scs;
  char* dst = lds + t * 16;

  int offA[MT], offB[NTF];
#pragma unroll
  for (int mi = 0; mi < MT; ++mi) {
    int o = (wm * PM + mi * 16 + rlo) * 64 + khi * 16;
    o ^= ((o >> 7) & 3) << 4;
    offA[mi] = o;
  }
#pragma unroll
  for (int ni = 0; ni < NTF; ++ni) {
    int o = (wn * PN + ni * 16 + rlo) * 64 + khi * 16;
    o ^= ((o >> 7) & 3) << 4;
    offB[ni] = o + BM * 64;
  }

  f32x4v acc[MT][NTF];
#pragma unroll
  for (int mi = 0; mi < MT; ++mi)
#pragma unroll
    for (int ni = 0; ni < NTF; ++ni) acc[mi][ni] = (f32x4v){0.f, 0.f, 0.f, 0.f};

#define STG(PS, R)                                                           \
  do {                                                                       \
    int kts_ = ((PS) >> 1 < NT) ? ((PS) >> 1) : NT - 1;                      \
    size_t co_ = (size_t)kts_ * 128 + (size_t)((PS) & 1) * 64;               \
    char* d_ = dst + (size_t)(R) * REG;                                      \
    _Pragma("unroll") for (int i_ = 0; i_ < NA; ++i_)                        \
        gld_lds16(Ap[i_] + co_, d_ + i_ * 8192);                             \
    _Pragma("unroll") for (int i_ = 0; i_ < NB; ++i_)                        \
        gld_lds16(Bp[i_] + co_, d_ + BM * 64 + i_ * 8192);                   \
  } while (0)

  STG(0, 0); STG(1, 1); STG(2, 2);
  waitcnt_vm<LPS>();
  __builtin_amdgcn_s_barrier();
  __builtin_amdgcn_sched_barrier(0);

  int rA = 0;
#pragma unroll 1
  for (int q = 0; q < NPH / 2; ++q) {
    const int p0 = q * 2;
    int rB = rA + 1; if (rB >= 5) rB -= 5;
    int tA = rA + 3; if (tA >= 5) tA -= 5;
    int tB = rA + 4; if (tB >= 5) tB -= 5;

    {
      const char* rb = lds + (size_t)rA * REG;
      bf16x8 af[MT], bv[NTF];
#pragma unroll
      for (int mi = 0; mi < MT; ++mi) af[mi] = *(const bf16x8*)(rb + offA[mi]);
#pragma unroll
      for (int ni = 0; ni < NTF; ++ni) bv[ni] = *(const bf16x8*)(rb + offB[ni]);
      STG(p0 + 3, tA);
      __builtin_amdgcn_s_setprio(1);
#pragma unroll
      for (int mi = 0; mi < MT; ++mi)
#pragma unroll
        for (int ni = 0; ni < NTF; ++ni)
          acc[mi][ni] = __builtin_amdgcn_mfma_f32_16x16x32_bf16(af[mi], bv[ni], acc[mi][ni], 0, 0, 0);
      __builtin_amdgcn_s_setprio(0);
    }
    {
      const char* rb = lds + (size_t)rB * REG;
      bf16x8 af[MT], bv[NTF];
#pragma unroll
      for (int mi = 0; mi < MT; ++mi) af[mi] = *(const bf16x8*)(rb + offA[mi]);
#pragma unroll
      for (int ni = 0; ni < NTF; ++ni) bv[ni] = *(const bf16x8*)(rb + offB[ni]);
      STG(p0 + 4, tB);
      __builtin_amdgcn_s_setprio(1);
#pragma unroll
      for (int mi = 0; mi < MT; ++mi)
#pragma unroll
        for (int ni = 0; ni < NTF; ++ni)
          acc[mi][ni] = __builtin_amdgcn_mfma_f32_16x16x32_bf16(af[mi], bv[ni], acc[mi][ni], 0, 0, 0);
      __builtin_amdgcn_s_setprio(0);
    }
    waitcnt_vm<LPS>();
    __builtin_amdgcn_s_barrier();
    __builtin_amdgcn_sched_barrier(0);
    rA += 2; if (rA >= 5) rA -= 5;
  }
#undef STG
  waitcnt_vm<0>();

  const int mrb = khi * 4;
#pragma unroll
  for (int mi = 0; mi < MT; ++mi)
#pragma unroll
    for (int ni = 0; ni < NTF; ++ni)
#pragma unroll
      for (int r = 0; r < 4; ++r) {
        int mm = m0 + wm * PM + mi * 16 + mrb + r;
        int nn = n0 + wn * PN + ni * 16 + rlo;
        float v = acc[mi][ni][r];
        if (OUT_BF16) ((unsigned short*)Cg)[(size_t)mm * ldc + nn] = f2bf(v);
        else          ((float*)Cg)[(size_t)mm * ldc + nn] = v;
      }
}

// ---------------------------------------------------------------- causal conv K=4 + SiLU
__global__ __launch_bounds__(256) void conv_silu_kernel(const unsigned short* __restrict__ C1,
                                                        const float* __restrict__ conv_w,
                                                        unsigned short* __restrict__ QKV) {
  int idx = blockIdx.x * 256 + threadIdx.x;       // (ROWS/8) * 2048
  int nb = idx >> 11;
  int c4 = (idx & 2047) << 2;
  int row0 = nb * 8;
  int s0 = row0 & 2047;
  float4 w0 = *(const float4*)(conv_w + (size_t)(c4 + 0) * 4);
  float4 w1 = *(const float4*)(conv_w + (size_t)(c4 + 1) * 4);
  float4 w2 = *(const float4*)(conv_w + (size_t)(c4 + 2) * 4);
  float4 w3 = *(const float4*)(conv_w + (size_t)(c4 + 3) * 4);
  const float* pw0 = (const float*)&w0;
  const float* pw1 = (const float*)&w1;
  const float* pw2 = (const float*)&w2;
  const float* pw3 = (const float*)&w3;
  ushort4 rw[11];
#pragma unroll
  for (int i = 0; i < 11; ++i) {
    if (s0 + i >= 3) rw[i] = *(const ushort4*)(C1 + (size_t)(row0 - 3 + i) * LDC1 + c4);
    else { rw[i].x = 0; rw[i].y = 0; rw[i].z = 0; rw[i].w = 0; }
  }
#pragma unroll
  for (int j = 0; j < 8; ++j) {
    float a0 = 0.f, a1 = 0.f, a2 = 0.f, a3 = 0.f;
#pragma unroll
    for (int jj = 0; jj < 4; ++jj) {
      ushort4 mv = rw[j + jj];
      a0 += bf2f(mv.x) * pw0[jj];
      a1 += bf2f(mv.y) * pw1[jj];
      a2 += bf2f(mv.z) * pw2[jj];
      a3 += bf2f(mv.w) * pw3[jj];
    }
    ushort4 o;
    o.x = f2bf(a0 / (1.f + __expf(-a0)));
    o.y = f2bf(a1 / (1.f + __expf(-a1)));
    o.z = f2bf(a2 / (1.f + __expf(-a2)));
    o.w = f2bf(a3 / (1.f + __expf(-a3)));
    *(ushort4*)(QKV + (size_t)(row0 + j) * LDQ + c4) = o;
  }
}

// ---------------------------------------------------------------- INTRA: per-chunk solve
// k/q already normalized in QKV (qknorm): staging is a copy; rhs uses bf16 kn.
#define INTRA_SMEM 52736
__global__ __launch_bounds__(256, 3) void intra_kernel(const unsigned short* __restrict__ QKV,
                                                       const float* __restrict__ G,
                                                       const float* __restrict__ BETA,
                                                       unsigned short* __restrict__ WU,
                                                       unsigned short* __restrict__ ATTN) {
  extern __shared__ char smem[];
  unsigned short* ktb = (unsigned short*)smem;        // [64][136] bf16
  float* Amat = (float*)(smem + 17408);               // [64][68] f32
  unsigned short* XtB = (unsigned short*)(smem + 34816);  // [128][68] bf16
  unsigned short* qb = XtB;                           // [64][136] alias (after solves)
  float* gc  = (float*)(smem + 52224);                // [64]
  float* bet = gc + 64;                               // [64]

  const int t = threadIdx.x;
  const int lane = t & 63, w = t >> 6;
  const int rlo = lane & 15, khi = lane >> 4;
  const int cix = blockIdx.x & 31;
  const int h = (blockIdx.x >> 5) & 31;
  const int b = blockIdx.x >> 10;
  const int hq = h >> 1;
  const int row0 = cix * 64;
  const size_t rowbase = (size_t)b * SEQ;

  if (t < 64) {
    float gv = G[(rowbase + row0 + t) * NUMV + h];
    bet[t] = BETA[(rowbase + row0 + t) * NUMV + h];
#pragma unroll
    for (int off = 1; off < 64; off <<= 1) {
      float u = __shfl_up(gv, off, 64);
      if (t >= off) gv += u;
    }
    gc[t] = gv;
  }
  __syncthreads();

  const int r = t >> 2, q4 = t & 3;
  const size_t grow = (rowbase + row0 + r) * (size_t)LDQ;

  // P1: normalized k copy -> ktb ; rhs = kn * e^gc * beta -> XtB
  {
    const unsigned short* kp = QKV + grow + 2048 + hq * 128 + q4 * 32;
    unsigned short knb[32];
#pragma unroll
    for (int j = 0; j < 32; j += 8) {
      *(uint4*)&knb[j] = *(const uint4*)(kp + j);
      *(uint4*)&ktb[r * 136 + q4 * 32 + j] = *(const uint4*)&knb[j];
    }
    const float ekr = __expf(gc[r]) * bet[r];
#pragma unroll
    for (int j = 0; j < 32; ++j)
      XtB[(q4 * 32 + j) * 68 + r] = f2bf(bf2f(knb[j]) * ekr);
  }
  __syncthreads();

  float xr[64];

  {
    static const signed char SJ[10][2] = {{0,0},{1,0},{1,1},{2,0},{2,1},{2,2},{3,0},{3,1},{3,2},{3,3}};
    static const signed char SB[5] = {0, 3, 6, 8, 10};
    for (int sj = SB[w]; sj < SB[w + 1]; ++sj) {
      const int mt = SJ[sj][0], nt = SJ[sj][1];
      f32x4v acc = (f32x4v){0.f, 0.f, 0.f, 0.f};
#pragma unroll
      for (int ks = 0; ks < 4; ++ks) {
        bf16x8 af = *(const bf16x8*)&ktb[(mt * 16 + rlo) * 136 + ks * 32 + khi * 8];
        bf16x8 bf_ = *(const bf16x8*)&ktb[(nt * 16 + rlo) * 136 + ks * 32 + khi * 8];
        acc = __builtin_amdgcn_mfma_f32_16x16x32_bf16(af, bf_, acc, 0, 0, 0);
      }
      const int j = nt * 16 + rlo;
#pragma unroll
      for (int r2 = 0; r2 < 4; ++r2) {
        const int i = mt * 16 + khi * 4 + r2;
        if (j < i) Amat[i * 68 + j] = -bet[i] * __expf(gc[i] - gc[j]) * acc[r2];
      }
    }
    if (t < 128) {
      const unsigned short* Xc = XtB + t * 68;
#pragma unroll
      for (int j = 0; j < 64; j += 4) {
        ushort4 xv = *(const ushort4*)(Xc + j);
        xr[j] = bf2f(xv.x); xr[j + 1] = bf2f(xv.y); xr[j + 2] = bf2f(xv.z); xr[j + 3] = bf2f(xv.w);
      }
    }
  }
  __syncthreads();

  {
    const unsigned short* vp = QKV + grow + 4096 + h * 128 + q4 * 32;
    const float brow = bet[r];
#pragma unroll
    for (int j = 0; j < 32; j += 4) {
      ushort4 vm = *(const ushort4*)(vp + j);
      XtB[(q4 * 32 + j + 0) * 68 + r] = f2bf(bf2f(vm.x) * brow);
      XtB[(q4 * 32 + j + 1) * 68 + r] = f2bf(bf2f(vm.y) * brow);
      XtB[(q4 * 32 + j + 2) * 68 + r] = f2bf(bf2f(vm.z) * brow);
      XtB[(q4 * 32 + j + 3) * 68 + r] = f2bf(bf2f(vm.w) * brow);
    }
  }
  __syncthreads();
  if (t >= 128) {
    const unsigned short* Xc = XtB + (t - 128) * 68;
#pragma unroll
    for (int j = 0; j < 64; j += 4) {
      ushort4 xv = *(const ushort4*)(Xc + j);
      xr[j] = bf2f(xv.x); xr[j + 1] = bf2f(xv.y); xr[j + 2] = bf2f(xv.z); xr[j + 3] = bf2f(xv.w);
    }
  }
  __syncthreads();

#pragma unroll
  for (int ib = 0; ib < 8; ++ib) {
    const int i0 = ib * 8;
    float p[8] = {0, 0, 0, 0, 0, 0, 0, 0};
#pragma unroll
    for (int j = 0; j < i0; j += 4) {
#pragma unroll
      for (int r2 = 0; r2 < 8; ++r2) {
        f32x4v ar = *(const f32x4v*)&Amat[(i0 + r2) * 68 + j];
        p[r2] += ar[0] * xr[j] + ar[1] * xr[j + 1] + ar[2] * xr[j + 2] + ar[3] * xr[j + 3];
      }
    }
#pragma unroll
    for (int r2 = 0; r2 < 8; ++r2) {
      float v = xr[i0 + r2] + p[r2];
#pragma unroll
      for (int r3 = 0; r3 < r2; ++r3) v += Amat[(i0 + r2) * 68 + i0 + r3] * xr[i0 + r3];
      xr[i0 + r2] = v;
    }
  }

  if (t < 128) {
    unsigned short* Xc = XtB + t * 68;
#pragma unroll
    for (int j = 0; j < 64; j += 4) {
      ushort4 xv;
      xv.x = f2bf(xr[j]); xv.y = f2bf(xr[j + 1]); xv.z = f2bf(xr[j + 2]); xv.w = f2bf(xr[j + 3]);
      *(ushort4*)(Xc + j) = xv;
    }
  }
  __syncthreads();
  {
    unsigned short* wdst = WU + (rowbase + row0 + r) * (size_t)LDC1 + h * 128 + q4 * 32;
#pragma unroll
    for (int j = 0; j < 32; ++j) wdst[j] = XtB[(q4 * 32 + j) * 68 + r];
  }
  __syncthreads();
  if (t >= 128) {
    unsigned short* Xc = XtB + (t - 128) * 68;
#pragma unroll
    for (int j = 0; j < 64; j += 4) {
      ushort4 xv;
      xv.x = f2bf(xr[j]); xv.y = f2bf(xr[j + 1]); xv.z = f2bf(xr[j + 2]); xv.w = f2bf(xr[j + 3]);
      *(ushort4*)(Xc + j) = xv;
    }
  }
  __syncthreads();
  {
    unsigned short* udst = WU + (rowbase + row0 + r) * (size_t)LDC1 + 4096 + h * 128 + q4 * 32;
#pragma unroll
    for (int j = 0; j < 32; ++j) udst[j] = XtB[(q4 * 32 + j) * 68 + r];
  }
  __syncthreads();

  // q copy (already normalized+scaled in place)
  {
    const unsigned short* qp = QKV + grow + hq * 128 + q4 * 32;
#pragma unroll
    for (int j = 0; j < 32; j += 8)
      *(uint4*)&qb[r * 136 + q4 * 32 + j] = *(const uint4*)(qp + j);
  }
  __syncthreads();

  {
    const size_t abase = (((size_t)b * 32 + h) * 32 + cix) * 4096;
    static const signed char CJ[10][2] = {{0,0},{1,0},{1,1},{2,0},{2,1},{2,2},{3,0},{3,1},{3,2},{3,3}};
    static const signed char CB[5] = {0, 3, 6, 8, 10};
    static const signed char ZJ[6][2] = {{0,1},{0,2},{0,3},{1,2},{1,3},{2,3}};
    static const signed char ZB[5] = {0, 0, 0, 3, 6};
#pragma unroll 1
    for (int cj = CB[w]; cj < CB[w + 1]; ++cj) {
      const int bi = CJ[cj][0], nt = CJ[cj][1];
      const int j = nt * 16 + rlo;
      f32x4v acc = (f32x4v){0.f, 0.f, 0.f, 0.f};
#pragma unroll
      for (int ks = 0; ks < 4; ++ks) {
        bf16x8 af = *(const bf16x8*)&qb[(bi * 16 + rlo) * 136 + ks * 32 + khi * 8];
        bf16x8 bf_ = *(const bf16x8*)&ktb[(nt * 16 + rlo) * 136 + ks * 32 + khi * 8];
        acc = __builtin_amdgcn_mfma_f32_16x16x32_bf16(af, bf_, acc, 0, 0, 0);
      }
#pragma unroll
      for (int r2 = 0; r2 < 4; ++r2) {
        const int i = bi * 16 + khi * 4 + r2;
        float v = (j <= i) ? __expf(gc[i] - gc[j]) * acc[r2] : 0.f;
        ATTN[abase + i * 64 + j] = f2bf(v);
      }
    }
#pragma unroll 1
    for (int zj = ZB[w]; zj < ZB[w + 1]; ++zj) {
      const int bi = ZJ[zj][0], nt = ZJ[zj][1];
#pragma unroll
      for (int r2 = 0; r2 < 4; ++r2)
        ATTN[abase + (bi * 16 + khi * 4 + r2) * 64 + nt * 16 + rlo] = 0;
    }
  }
}

// ---------------------------------------------------------------- SEQ: state recurrence
// ktT from KNT (copy); q frags loaded directly (already normalized) -> no q math.
#define SEQ_SMEM 70400
__global__ __launch_bounds__(256) void seq_kernel(const unsigned short* __restrict__ QKV,
                                                  const float* __restrict__ G,
                                                  const unsigned short* __restrict__ WU,
                                                  const unsigned short* __restrict__ ATTN,
                                                  const unsigned short* __restrict__ KNT,
                                                  unsigned short* __restrict__ CORE) {
  extern __shared__ char smem[];
  unsigned short* ktT    = (unsigned short*)smem;            // [128][88]
  unsigned short* wb     = (unsigned short*)(smem + 22528);  // [64][136]
  unsigned short* attnb  = (unsigned short*)(smem + 39936);  // [64][88]
  float* stateT          = (float*)(smem + 51200);           // [16][136]
  unsigned short* stateTb = (unsigned short*)(smem + 59904); // [16][136]
  unsigned short* vnTb   = (unsigned short*)(smem + 64256);  // [16][88]
  unsigned short* vdTb   = (unsigned short*)(smem + 67072);  // [16][88]

  const int t = threadIdx.x;
  const int lane = t & 63, w = t >> 6;
  const int rlo = lane & 15, khi = lane >> 4;
  const int vq = blockIdx.x & 7;
  const int h = (blockIdx.x >> 3) & 31;
  const int b = blockIdx.x >> 8;
  const int hq = h >> 1;
  const size_t rowbase = (size_t)b * SEQ;
  const size_t ahead = ((size_t)b * 32 + h) * 32;
  const size_t knbase = (((size_t)b * 16 + hq) * 32) << 13;

  for (int i = t; i < 16 * 136; i += 256) { stateT[i] = 0.f; stateTb[i] = 0; }
  __syncthreads();

  bf16x8 qf[4];

#pragma unroll 1
  for (int ncb = 0; ncb < 32; ++ncb) {
    const int row0 = ncb * 64;

    float gv = G[(rowbase + row0 + lane) * NUMV + h];
#pragma unroll
    for (int off = 1; off < 64; off <<= 1) {
      float uph = __shfl_up(gv, off, 64);
      if (lane >= off) gv += uph;
    }
    const float gtot = __shfl(gv, 63, 64);

    {
      const int r = t >> 2, q4 = t & 3;
      const unsigned short* ksrc = KNT + knbase + ((size_t)ncb << 13) + (size_t)t * 32;
      unsigned short* kdst = ktT + (t >> 1) * 88 + (t & 1) * 32;
#pragma unroll
      for (int j = 0; j < 4; ++j)
        *(uint4*)(kdst + j * 8) = *(const uint4*)(ksrc + j * 8);
      const unsigned short* wsrc = WU + (rowbase + row0 + r) * (size_t)LDC1 + h * 128 + q4 * 32;
#pragma unroll
      for (int u2 = 0; u2 < 4; ++u2)
        *(uint4*)&wb[r * 136 + q4 * 32 + u2 * 8] = *(const uint4*)(wsrc + u2 * 8);
      const unsigned short* asrc = ATTN + (ahead + ncb) * 4096 + r * 64 + q4 * 16;
      *(uint4*)&attnb[r * 88 + q4 * 16] = *(const uint4*)(asrc);
      *(uint4*)&attnb[r * 88 + q4 * 16 + 8] = *(const uint4*)(asrc + 8);
      // q frags: already normalized in place — pure bitcast load
      const unsigned short* qsrc = QKV + (rowbase + row0 + w * 16 + rlo) * (size_t)LDQ + hq * 128 + khi * 8;
#pragma unroll
      for (int ks = 0; ks < 4; ++ks) {
        ushort4 qa = *(const ushort4*)(qsrc + ks * 32);
        ushort4 qb2 = *(const ushort4*)(qsrc + ks * 32 + 4);
        bf16x8 tv;
        tv[0] = (short)qa.x; tv[1] = (short)qa.y; tv[2] = (short)qa.z; tv[3] = (short)qa.w;
        tv[4] = (short)qb2.x; tv[5] = (short)qb2.y; tv[6] = (short)qb2.z; tv[7] = (short)qb2.w;
        qf[ks] = tv;
      }
    }
    __syncthreads();

    f32x4v oacc;
    {
      f32x4v pacc = (f32x4v){0.f, 0.f, 0.f, 0.f};
      oacc = (f32x4v){0.f, 0.f, 0.f, 0.f};
#pragma unroll
      for (int ks = 0; ks < 4; ++ks) {
        bf16x8 aw = *(const bf16x8*)&wb[(w * 16 + rlo) * 136 + ks * 32 + khi * 8];
        bf16x8 bs = *(const bf16x8*)&stateTb[rlo * 136 + ks * 32 + khi * 8];
        pacc = __builtin_amdgcn_mfma_f32_16x16x32_bf16(aw, bs, pacc, 0, 0, 0);
        oacc = __builtin_amdgcn_mfma_f32_16x16x32_bf16(qf[ks], bs, oacc, 0, 0, 0);
      }
#pragma unroll
      for (int r2 = 0; r2 < 4; ++r2) {
        const int i = w * 16 + khi * 4 + r2;
        const float gci = __shfl(gv, i, 64);
        float uv = bf2f(WU[(rowbase + row0 + i) * (size_t)LDC1 + 4096 + h * 128 + vq * 16 + rlo]);
        float vn = uv - pacc[r2];
        vnTb[rlo * 88 + i] = f2bf(vn);
        vdTb[rlo * 88 + i] = f2bf(vn * __expf(gtot - gci));
        oacc[r2] *= __expf(gci);
      }
    }
    __syncthreads();

    {
#pragma unroll
      for (int ks = 0; ks < 2; ++ks) {
        bf16x8 aa = *(const bf16x8*)&attnb[(w * 16 + rlo) * 88 + ks * 32 + khi * 8];
        bf16x8 bv = *(const bf16x8*)&vnTb[rlo * 88 + ks * 32 + khi * 8];
        oacc = __builtin_amdgcn_mfma_f32_16x16x32_bf16(aa, bv, oacc, 0, 0, 0);
      }
      const int col = h * 128 + vq * 16 + rlo;
#pragma unroll
      for (int r2 = 0; r2 < 4; ++r2) {
        const int i = w * 16 + khi * 4 + r2;
        CORE[(rowbase + row0 + i) * (size_t)LDCO + col] = f2bf(oacc[r2]);
      }
      const float egl = __expf(gtot);
#pragma unroll
      for (int n2 = 0; n2 < 2; ++n2) {
        const int dt = w * 2 + n2;
        f32x4v sacc = (f32x4v){0.f, 0.f, 0.f, 0.f};
#pragma unroll
        for (int ks = 0; ks < 2; ++ks) {
          bf16x8 ak = *(const bf16x8*)&ktT[(dt * 16 + rlo) * 88 + ks * 32 + khi * 8];
          bf16x8 bv2 = *(const bf16x8*)&vdTb[rlo * 88 + ks * 32 + khi * 8];
          sacc = __builtin_amdgcn_mfma_f32_16x16x32_bf16(ak, bv2, sacc, 0, 0, 0);
        }
#pragma unroll
        for (int r2 = 0; r2 < 4; ++r2) {
          const int d = dt * 16 + khi * 4 + r2;
          float ns = stateT[rlo * 136 + d] * egl + sacc[r2];
          stateT[rlo * 136 + d] = ns;
          stateTb[rlo * 136 + d] = f2bf(ns);
        }
      }
    }
    __syncthreads();
  }
}

// ---------------------------------------------------------------- gate * silu(z) + RMS-norm
__global__ __launch_bounds__(256) void gatenorm_kernel(const unsigned short* __restrict__ CORE,
                                                       const unsigned short* __restrict__ C1,
                                                       const float* __restrict__ norm_w,
                                                       unsigned short* __restrict__ NRM) {
  const int wid = blockIdx.x * 4 + (threadIdx.x >> 6);
  const int lane = threadIdx.x & 63;
  const int row = wid >> 5, h = wid & 31;
  const int c = lane * 2;
  const size_t cidx = (size_t)row * LDCO + h * 128 + c;
  const size_t zidx = (size_t)row * LDC1 + 8192 + h * 128 + c;
  float g0 = bf2f(CORE[cidx]), g1 = bf2f(CORE[cidx + 1]);
  float z0 = bf2f(C1[zidx]), z1 = bf2f(C1[zidx + 1]);
  g0 *= z0 / (1.f + __expf(-z0));
  g1 *= z1 / (1.f + __expf(-z1));
  float ss = g0 * g0 + g1 * g1;
#pragma unroll
  for (int m = 1; m < 64; m <<= 1) ss += __shfl_xor(ss, m, 64);
  const float rr = rsqrtf(ss * (1.f / 128.f) + 1e-6f);
  unsigned int o = ((unsigned int)f2bf(g1 * rr * norm_w[c + 1]) << 16) | (unsigned int)f2bf(g0 * rr * norm_w[c]);
  *(unsigned int*)(NRM + cidx) = o;
}

// ---------------------------------------------------------------------------
extern "C" void kernel_launch(void* const* d_in, const int* in_sizes, int n_in,
                              void* d_out, int out_size, void* d_ws, size_t ws_size,
                              hipStream_t stream) {
  const float* hs      = (const float*)d_in[0];
  const float* W_qkv   = (const float*)d_in[1];
  const float* W_z     = (const float*)d_in[2];
  const float* W_b     = (const float*)d_in[3];
  const float* W_a     = (const float*)d_in[4];
  const float* conv_w  = (const float*)d_in[5];
  const float* dt_bias = (const float*)d_in[6];
  const float* A_log   = (const float*)d_in[7];
  const float* norm_w  = (const float*)d_in[8];
  const float* W_out   = (const float*)d_in[9];
  float* out = (float*)d_out;
  char* ws = (char*)d_ws;

  const size_t OFF_HSB = 0;                                     // hsb[4096][2080]; later ATTN
  const size_t OFF_WT  = OFF_HSB + (size_t)ROWS * LDH * 2;      // WT[12288][2080]; later CORE+KNT
  const size_t OFF_WOT = OFF_WT + (size_t)NWP * LDW * 2;        // WoT[2048][4160]
  const size_t OFF_WBA = OFF_WOT + (size_t)HIDN * LDWO * 2;     // WbaK[2048][64]
  const size_t OFF_C1  = OFF_WBA + (size_t)2048 * 64 * 2;       // C1[4096][12416]
  const size_t OFF_QKV = OFF_C1 + (size_t)ROWS * LDC1 * 2;      // QKV[4096][8256]; later NRM
  const size_t OFF_G   = OFF_QKV + (size_t)ROWS * LDQ * 2;
  const size_t OFF_B   = OFF_G + (size_t)ROWS * NUMV * 4;
  const size_t OFF_KNT = OFF_WT + (size_t)ROWS * LDCO * 2;      // after CORE, inside old WT

  unsigned short* hsb = (unsigned short*)(ws + OFF_HSB);
  unsigned short* WT  = (unsigned short*)(ws + OFF_WT);
  unsigned short* WoT = (unsigned short*)(ws + OFF_WOT);
  unsigned short* Wba = (unsigned short*)(ws + OFF_WBA);
  unsigned short* C1  = (unsigned short*)(ws + OFF_C1);
  unsigned short* QKV = (unsigned short*)(ws + OFF_QKV);
  float* Gb = (float*)(ws + OFF_G);
  float* Bb = (float*)(ws + OFF_B);
  unsigned short* ATTNb = (unsigned short*)(ws + OFF_HSB);
  unsigned short* COREb = (unsigned short*)(ws + OFF_WT);
  unsigned short* KNTb  = (unsigned short*)(ws + OFF_KNT);
  unsigned short* NRMb  = (unsigned short*)(ws + OFF_QKV);

  cast_kernel<<<ROWS, 256, 0, stream>>>(hs, hsb);
  transpose_kernel<<<dim3(8192 / 64, 2048 / 64), 256, 0, stream>>>(W_qkv, WT, 2048, 8192, LDW, 0);
  transpose_kernel<<<dim3(4096 / 64, 2048 / 64), 256, 0, stream>>>(W_z, WT, 2048, 4096, LDW, 8192);
  bacat_kernel<<<2048 * 64 / 256, 256, 0, stream>>>(W_b, W_a, Wba);
  transpose_kernel<<<dim3(2048 / 64, 4096 / 64), 256, 0, stream>>>(W_out, WoT, 4096, 2048, LDWO, 0);

  ba_kernel<<<ROWS / 8, 256, 0, stream>>>(hsb, Wba, dt_bias, A_log, Gb, Bb);

  void (*g1p)(const unsigned short*, const unsigned short*, void*, int, int, int, int, int, int) =
      gemm_r5_kernel<256, 256, 1>;
  void (*g0p)(const unsigned short*, const unsigned short*, void*, int, int, int, int, int, int) =
      gemm_r5_kernel<128, 256, 0>;
  hipFuncSetAttribute((const void*)g1p, hipFuncAttributeMaxDynamicSharedMemorySize, 5 * (256 + 256) * 64);
  hipFuncSetAttribute((const void*)g0p, hipFuncAttributeMaxDynamicSharedMemorySize, 5 * (128 + 256) * 64);

  gemm_r5_kernel<256, 256, 1><<<dim3(NWP / 256, ROWS / 256), 512, 5 * (256 + 256) * 64, stream>>>(
      hsb, WT, C1, ROWS, NWP, HIDN, LDH, LDW, LDC1);
  conv_silu_kernel<<<(ROWS / 8) * 2048 / 256, 256, 0, stream>>>(C1, conv_w, QKV);

  qknorm_kernel<<<2 * 16 * 32, 256, 0, stream>>>(QKV, KNTb);

  hipFuncSetAttribute((const void*)intra_kernel, hipFuncAttributeMaxDynamicSharedMemorySize,
                      INTRA_SMEM);
  intra_kernel<<<2048, 256, INTRA_SMEM, stream>>>(QKV, Gb, Bb, C1, ATTNb);

  hipFuncSetAttribute((const void*)seq_kernel, hipFuncAttributeMaxDynamicSharedMemorySize,
                      SEQ_SMEM);
  seq_kernel<<<512, 256, SEQ_SMEM, stream>>>(QKV, Gb, C1, ATTNb, KNTb, COREb);

  gatenorm_kernel<<<ROWS * NUMV / 4, 256, 0, stream>>>(COREb, C1, norm_w, NRMb);
  gemm_r5_kernel<128, 256, 0><<<dim3(2048 / 256, ROWS / 128), 512, 5 * (128 + 256) * 64, stream>>>(
      NRMb, WoT, out, ROWS, 2048, 4096, LDCO, LDWO, 2048);
}

// Round 20
// 700.011 us; speedup vs baseline: 1.0121x; 1.0121x over previous
//
#include <hip/hip_runtime.h>
#include <cstdint>
#include <cstddef>

// ---------------------------------------------------------------------------
// GatedDeltaNet forward, MI355X/gfx950.
// R20 = R18 (revert of R19's q-dedup, which regressed +9us: seq's q math was
// latency-hidden; qknorm's serialized QKV rewrite cost more than it saved).
// R18 = knorm dedup (k-norm once per (b,hq,chunk), pre-transposed KNT) +
// intra bf16 staging (3 WG/CU) + ring-5 GEMMs + all prior banked wins.
// ---------------------------------------------------------------------------

#define ROWS  4096
#define SEQ   2048
#define HIDN  2048
#define NWP   12288     // logical N of GEMM1 (48 tiles)
#define NUMV  32

#define LDH   2080      // hsb row stride (elems)
#define LDW   2080      // WT row stride
#define LDWO  4160      // WoT row stride
#define LDC1  12416     // C1 / WU row stride
#define LDQ   8256      // QKV row stride
#define LDCO  4160      // CORE / NRM row stride

using bf16x8 = __attribute__((ext_vector_type(8))) short;
using f32x4v = __attribute__((ext_vector_type(4))) float;

__device__ __forceinline__ float bf2f(unsigned short u) {
  union { unsigned int i; float f; } x; x.i = ((unsigned int)u) << 16; return x.f;
}
__device__ __forceinline__ unsigned short f2bf(float f) {
  union { float f; unsigned int u; } x; x.f = f;
  unsigned int u = x.u;
  unsigned int r = (u + 0x7FFFu + ((u >> 16) & 1u)) >> 16;  // RNE
  return (unsigned short)r;
}

typedef const __attribute__((address_space(1))) unsigned int GU32;
typedef __attribute__((address_space(3))) unsigned int LU32;
__device__ __forceinline__ void gld_lds16(const void* g, void* l) {
  GU32* gp = (GU32*)(unsigned long long)(uintptr_t)g;
  LU32* lp = (LU32*)(unsigned int)(uintptr_t)l;  // flat-LDS low32 = LDS offset
  __builtin_amdgcn_global_load_lds(gp, lp, 16, 0, 0);
}
template <int N>
__device__ __forceinline__ void waitcnt_vm() {
  asm volatile("s_waitcnt vmcnt(%0)" ::"i"(N) : "memory");
}

// ---------------------------------------------------------------- cast fp32->bf16 (ld-padded)
__global__ __launch_bounds__(256) void cast_kernel(const float* __restrict__ in,
                                                   unsigned short* __restrict__ out) {
  int i = blockIdx.x * 256 + threadIdx.x;   // ROWS * 256
  int row = i >> 8;
  int c8 = (i & 255) * 8;
  float4 v0 = *(const float4*)(in + (size_t)row * 2048 + c8);
  float4 v1 = *(const float4*)(in + (size_t)row * 2048 + c8 + 4);
  unsigned short o[8];
  o[0] = f2bf(v0.x); o[1] = f2bf(v0.y); o[2] = f2bf(v0.z); o[3] = f2bf(v0.w);
  o[4] = f2bf(v1.x); o[5] = f2bf(v1.y); o[6] = f2bf(v1.z); o[7] = f2bf(v1.w);
  *(uint4*)(out + (size_t)row * LDH + c8) = *(const uint4*)o;
}

// ------------------------------------------------- transpose W[K][N] -> WT[roff+N][K] (ld)
__global__ __launch_bounds__(256) void transpose_kernel(const float* __restrict__ W,
                                                        unsigned short* __restrict__ WT,
                                                        int K, int N, int ld, int roff) {
  __shared__ float tile[64][65];
  const int t = threadIdx.x;
  const int kb = blockIdx.y * 64, nb = blockIdx.x * 64;
  const int r = t >> 2, c0 = (t & 3) * 16;
#pragma unroll
  for (int i = 0; i < 16; ++i) {
    int c = c0 + i;
    float v = 0.f;
    if (nb + c < N) v = W[(size_t)(kb + r) * N + nb + c];
    tile[r][c] = v;
  }
  __syncthreads();
  const int bn = t >> 2, seg = (t & 3) * 16;
  if (nb + bn < N) {
    unsigned short tmp[16];
#pragma unroll
    for (int i = 0; i < 16; ++i) tmp[i] = f2bf(tile[seg + i][bn]);
    unsigned short* dst = WT + (size_t)(roff + nb + bn) * ld + kb + seg;
    *(uint4*)dst = *(const uint4*)&tmp[0];
    *(uint4*)(dst + 8) = *(const uint4*)&tmp[8];
  }
}

// ---------------------------------------------------------------- WbaK[k][c] = [W_b | W_a] bf16
__global__ __launch_bounds__(256) void bacat_kernel(const float* __restrict__ Wb,
                                                    const float* __restrict__ Wa,
                                                    unsigned short* __restrict__ WbaK) {
  int idx = blockIdx.x * 256 + threadIdx.x;   // 2048*64
  int k = idx >> 6, c = idx & 63;
  float v = (c < 32) ? Wb[k * 32 + c] : Wa[k * 32 + (c - 32)];
  WbaK[idx] = f2bf(v);
}

// ---------------------------------------------------------------- b/a projections -> beta/g
__global__ __launch_bounds__(256) void ba_kernel(const unsigned short* __restrict__ hsb,
                                                 const unsigned short* __restrict__ WbaK,
                                                 const float* __restrict__ dt_bias,
                                                 const float* __restrict__ A_log,
                                                 float* __restrict__ G, float* __restrict__ BETA) {
  __shared__ unsigned short hsl[8][2048];   // 32 KB
  __shared__ float pacc[4][8][64];          // 8 KB
  const int t = threadIdx.x;
  const int lane = t & 63, w = t >> 6;
  const int row0 = blockIdx.x * 8;
#pragma unroll
  for (int rr = 0; rr < 2; ++rr) {
    const int r = w * 2 + rr;
    const unsigned short* src = hsb + (size_t)(row0 + r) * LDH + lane * 32;
#pragma unroll
    for (int j = 0; j < 8; ++j)
      *(ushort4*)&hsl[r][lane * 32 + j * 4] = *(const ushort4*)(src + j * 4);
  }
  __syncthreads();
  float acc[8] = {0.f, 0.f, 0.f, 0.f, 0.f, 0.f, 0.f, 0.f};
  const int kb0 = w * 512;
#pragma unroll 1
  for (int k = 0; k < 512; k += 4) {
    const unsigned short* wp = WbaK + (size_t)(kb0 + k) * 64 + lane;
    const float w0 = bf2f(wp[0]);
    const float w1 = bf2f(wp[64]);
    const float w2 = bf2f(wp[128]);
    const float w3 = bf2f(wp[192]);
#pragma unroll
    for (int r = 0; r < 8; ++r) {
      ushort4 hv = *(const ushort4*)&hsl[r][kb0 + k];
      acc[r] += bf2f(hv.x) * w0 + bf2f(hv.y) * w1 + bf2f(hv.z) * w2 + bf2f(hv.w) * w3;
    }
  }
#pragma unroll
  for (int r = 0; r < 8; ++r) pacc[w][r][lane] = acc[r];
  __syncthreads();
  const int r = t >> 5, hc = t & 31;
  float bp = pacc[0][r][hc] + pacc[1][r][hc] + pacc[2][r][hc] + pacc[3][r][hc];
  float ap = pacc[0][r][32 + hc] + pacc[1][r][32 + hc] + pacc[2][r][32 + hc] + pacc[3][r][32 + hc];
  const int idx = (row0 + r) * NUMV + hc;
  BETA[idx] = 1.f / (1.f + __expf(-bp));
  float x = ap + dt_bias[hc];
  float sp = (x > 15.f) ? x : log1pf(__expf(x));
  G[idx] = -__expf(A_log[hc]) * sp;
}

// ---------------------------------------------------------------- k-norm precompute -> KNT
// grid 1024 = b(2) x hq(16) x chunk(32). Computes kn with the EXACT expression
// seq used (bitwise-identical) and stores transposed KNT[d][i] bf16.
__global__ __launch_bounds__(256) void knorm_kernel(const unsigned short* __restrict__ QKV,
                                                    unsigned short* __restrict__ KNT) {
  const int t = threadIdx.x;
  const int chunk = blockIdx.x & 31;
  const int hq = (blockIdx.x >> 5) & 15;
  const int b = blockIdx.x >> 9;
  const int row0 = chunk * 64;
  const int r = t >> 2, q4 = t & 3;
  const size_t grow = ((size_t)b * SEQ + row0 + r) * (size_t)LDQ;
  const unsigned short* kp = QKV + grow + 2048 + hq * 128 + q4 * 32;
  float kv[32]; float ssk = 0.f;
#pragma unroll
  for (int j = 0; j < 32; j += 4) {
    ushort4 km = *(const ushort4*)(kp + j);
    kv[j] = bf2f(km.x); kv[j + 1] = bf2f(km.y); kv[j + 2] = bf2f(km.z); kv[j + 3] = bf2f(km.w);
    ssk += kv[j]*kv[j] + kv[j+1]*kv[j+1] + kv[j+2]*kv[j+2] + kv[j+3]*kv[j+3];
  }
  ssk += __shfl_xor(ssk, 1, 64);
  ssk += __shfl_xor(ssk, 2, 64);
  const float rk = rsqrtf(ssk + 1e-6f);
  unsigned short* kb = KNT + ((((size_t)b * 16 + hq) * 32 + chunk) << 13) + (size_t)(q4 * 32) * 64 + r;
#pragma unroll
  for (int j = 0; j < 32; ++j) kb[(size_t)j * 64] = f2bf(kv[j] * rk);
}

// ---------------------------------------------------------------- ring-5 pair-barrier GEMM
template <int BM, int BN, int OUT_BF16>
__global__ __launch_bounds__(512) void gemm_r5_kernel(const unsigned short* __restrict__ Ag,
                                                      const unsigned short* __restrict__ Bg,
                                                      void* __restrict__ Cg, int M, int N, int K,
                                                      int lda, int ldb, int ldc) {
  constexpr int PM = BM / 2, PN = BN / 4;
  constexpr int MT = PM / 16, NTF = PN / 16;
  constexpr int NA = BM / 128, NB = BN / 128;
  constexpr int LPS = NA + NB;
  constexpr int REG = (BM + BN) * 64;
  extern __shared__ char lds[];
  const int t = threadIdx.x;
  const int lane = t & 63, wid = t >> 6;
  const int wm = wid >> 2, wn = wid & 3;
  const int rlo = lane & 15, khi = lane >> 4;

  const int gx = gridDim.x, nwg = gx * gridDim.y;
  int id = blockIdx.y * gx + blockIdx.x;
  int sid = (id & 7) * (nwg >> 3) + (id >> 3);
  const int m0 = (sid / gx) * BM, n0 = (sid % gx) * BN;

  const int NT = K >> 6;
  const int NPH = NT * 2;

  const int srow = t >> 2;
  const int scs = ((t & 3) * 16) ^ (((t >> 3) & 3) << 4);
  const char* Ap[NA];
  const char* Bp[NB];
#pragma unroll
  for (int i = 0; i < NA; ++i)
    Ap[i] = (const char*)Ag + (size_t)(m0 + i * 128 + srow) * lda * 2 + scs;
#pragma unroll
  for (int i = 0; i < NB; ++i)
    Bp[i] = (const char*)Bg + (size_t)(n0 + i * 128 + srow) * ldb * 2 + scs;
  char* dst = lds + t * 16;

  int offA[MT], offB[NTF];
#pragma unroll
  for (int mi = 0; mi < MT; ++mi) {
    int o = (wm * PM + mi * 16 + rlo) * 64 + khi * 16;
    o ^= ((o >> 7) & 3) << 4;
    offA[mi] = o;
  }
#pragma unroll
  for (int ni = 0; ni < NTF; ++ni) {
    int o = (wn * PN + ni * 16 + rlo) * 64 + khi * 16;
    o ^= ((o >> 7) & 3) << 4;
    offB[ni] = o + BM * 64;
  }

  f32x4v acc[MT][NTF];
#pragma unroll
  for (int mi = 0; mi < MT; ++mi)
#pragma unroll
    for (int ni = 0; ni < NTF; ++ni) acc[mi][ni] = (f32x4v){0.f, 0.f, 0.f, 0.f};

#define STG(PS, R)                                                           \
  do {                                                                       \
    int kts_ = ((PS) >> 1 < NT) ? ((PS) >> 1) : NT - 1;                      \
    size_t co_ = (size_t)kts_ * 128 + (size_t)((PS) & 1) * 64;               \
    char* d_ = dst + (size_t)(R) * REG;                                      \
    _Pragma("unroll") for (int i_ = 0; i_ < NA; ++i_)                        \
        gld_lds16(Ap[i_] + co_, d_ + i_ * 8192);                             \
    _Pragma("unroll") for (int i_ = 0; i_ < NB; ++i_)                        \
        gld_lds16(Bp[i_] + co_, d_ + BM * 64 + i_ * 8192);                   \
  } while (0)

  STG(0, 0); STG(1, 1); STG(2, 2);
  waitcnt_vm<LPS>();
  __builtin_amdgcn_s_barrier();
  __builtin_amdgcn_sched_barrier(0);

  int rA = 0;
#pragma unroll 1
  for (int q = 0; q < NPH / 2; ++q) {
    const int p0 = q * 2;
    int rB = rA + 1; if (rB >= 5) rB -= 5;
    int tA = rA + 3; if (tA >= 5) tA -= 5;
    int tB = rA + 4; if (tB >= 5) tB -= 5;

    {
      const char* rb = lds + (size_t)rA * REG;
      bf16x8 af[MT], bv[NTF];
#pragma unroll
      for (int mi = 0; mi < MT; ++mi) af[mi] = *(const bf16x8*)(rb + offA[mi]);
#pragma unroll
      for (int ni = 0; ni < NTF; ++ni) bv[ni] = *(const bf16x8*)(rb + offB[ni]);
      STG(p0 + 3, tA);
      __builtin_amdgcn_s_setprio(1);
#pragma unroll
      for (int mi = 0; mi < MT; ++mi)
#pragma unroll
        for (int ni = 0; ni < NTF; ++ni)
          acc[mi][ni] = __builtin_amdgcn_mfma_f32_16x16x32_bf16(af[mi], bv[ni], acc[mi][ni], 0, 0, 0);
      __builtin_amdgcn_s_setprio(0);
    }
    {
      const char* rb = lds + (size_t)rB * REG;
      bf16x8 af[MT], bv[NTF];
#pragma unroll
      for (int mi = 0; mi < MT; ++mi) af[mi] = *(const bf16x8*)(rb + offA[mi]);
#pragma unroll
      for (int ni = 0; ni < NTF; ++ni) bv[ni] = *(const bf16x8*)(rb + offB[ni]);
      STG(p0 + 4, tB);
      __builtin_amdgcn_s_setprio(1);
#pragma unroll
      for (int mi = 0; mi < MT; ++mi)
#pragma unroll
        for (int ni = 0; ni < NTF; ++ni)
          acc[mi][ni] = __builtin_amdgcn_mfma_f32_16x16x32_bf16(af[mi], bv[ni], acc[mi][ni], 0, 0, 0);
      __builtin_amdgcn_s_setprio(0);
    }
    waitcnt_vm<LPS>();
    __builtin_amdgcn_s_barrier();
    __builtin_amdgcn_sched_barrier(0);
    rA += 2; if (rA >= 5) rA -= 5;
  }
#undef STG
  waitcnt_vm<0>();

  const int mrb = khi * 4;
#pragma unroll
  for (int mi = 0; mi < MT; ++mi)
#pragma unroll
    for (int ni = 0; ni < NTF; ++ni)
#pragma unroll
      for (int r = 0; r < 4; ++r) {
        int mm = m0 + wm * PM + mi * 16 + mrb + r;
        int nn = n0 + wn * PN + ni * 16 + rlo;
        float v = acc[mi][ni][r];
        if (OUT_BF16) ((unsigned short*)Cg)[(size_t)mm * ldc + nn] = f2bf(v);
        else          ((float*)Cg)[(size_t)mm * ldc + nn] = v;
      }
}

// ---------------------------------------------------------------- causal conv K=4 + SiLU
__global__ __launch_bounds__(256) void conv_silu_kernel(const unsigned short* __restrict__ C1,
                                                        const float* __restrict__ conv_w,
                                                        unsigned short* __restrict__ QKV) {
  int idx = blockIdx.x * 256 + threadIdx.x;       // (ROWS/8) * 2048
  int nb = idx >> 11;
  int c4 = (idx & 2047) << 2;
  int row0 = nb * 8;
  int s0 = row0 & 2047;
  float4 w0 = *(const float4*)(conv_w + (size_t)(c4 + 0) * 4);
  float4 w1 = *(const float4*)(conv_w + (size_t)(c4 + 1) * 4);
  float4 w2 = *(const float4*)(conv_w + (size_t)(c4 + 2) * 4);
  float4 w3 = *(const float4*)(conv_w + (size_t)(c4 + 3) * 4);
  const float* pw0 = (const float*)&w0;
  const float* pw1 = (const float*)&w1;
  const float* pw2 = (const float*)&w2;
  const float* pw3 = (const float*)&w3;
  ushort4 rw[11];
#pragma unroll
  for (int i = 0; i < 11; ++i) {
    if (s0 + i >= 3) rw[i] = *(const ushort4*)(C1 + (size_t)(row0 - 3 + i) * LDC1 + c4);
    else { rw[i].x = 0; rw[i].y = 0; rw[i].z = 0; rw[i].w = 0; }
  }
#pragma unroll
  for (int j = 0; j < 8; ++j) {
    float a0 = 0.f, a1 = 0.f, a2 = 0.f, a3 = 0.f;
#pragma unroll
    for (int jj = 0; jj < 4; ++jj) {
      ushort4 mv = rw[j + jj];
      a0 += bf2f(mv.x) * pw0[jj];
      a1 += bf2f(mv.y) * pw1[jj];
      a2 += bf2f(mv.z) * pw2[jj];
      a3 += bf2f(mv.w) * pw3[jj];
    }
    ushort4 o;
    o.x = f2bf(a0 / (1.f + __expf(-a0)));
    o.y = f2bf(a1 / (1.f + __expf(-a1)));
    o.z = f2bf(a2 / (1.f + __expf(-a2)));
    o.w = f2bf(a3 / (1.f + __expf(-a3)));
    *(ushort4*)(QKV + (size_t)(row0 + j) * LDQ + c4) = o;
  }
}

// ---------------------------------------------------------------- INTRA: per-chunk solve
#define INTRA_SMEM 52736
__global__ __launch_bounds__(256, 3) void intra_kernel(const unsigned short* __restrict__ QKV,
                                                       const float* __restrict__ G,
                                                       const float* __restrict__ BETA,
                                                       unsigned short* __restrict__ WU,
                                                       unsigned short* __restrict__ ATTN) {
  extern __shared__ char smem[];
  unsigned short* ktb = (unsigned short*)smem;        // [64][136] bf16
  float* Amat = (float*)(smem + 17408);               // [64][68] f32
  unsigned short* XtB = (unsigned short*)(smem + 34816);  // [128][68] bf16
  unsigned short* qb = XtB;                           // [64][136] alias (after solves)
  float* gc  = (float*)(smem + 52224);                // [64]
  float* bet = gc + 64;                               // [64]

  const int t = threadIdx.x;
  const int lane = t & 63, w = t >> 6;
  const int rlo = lane & 15, khi = lane >> 4;
  const int cix = blockIdx.x & 31;
  const int h = (blockIdx.x >> 5) & 31;
  const int b = blockIdx.x >> 10;
  const int hq = h >> 1;
  const int row0 = cix * 64;
  const size_t rowbase = (size_t)b * SEQ;

  if (t < 64) {
    float gv = G[(rowbase + row0 + t) * NUMV + h];
    bet[t] = BETA[(rowbase + row0 + t) * NUMV + h];
#pragma unroll
    for (int off = 1; off < 64; off <<= 1) {
      float u = __shfl_up(gv, off, 64);
      if (t >= off) gv += u;
    }
    gc[t] = gv;
  }
  __syncthreads();

  const int r = t >> 2, q4 = t & 3;
  const size_t grow = (rowbase + row0 + r) * (size_t)LDQ;

  {
    const unsigned short* kp = QKV + grow + 2048 + hq * 128 + q4 * 32;
    float kv[32]; float ssk = 0.f;
#pragma unroll
    for (int j = 0; j < 32; j += 4) {
      ushort4 km = *(const ushort4*)(kp + j);
      kv[j] = bf2f(km.x); kv[j + 1] = bf2f(km.y); kv[j + 2] = bf2f(km.z); kv[j + 3] = bf2f(km.w);
      ssk += kv[j]*kv[j] + kv[j+1]*kv[j+1] + kv[j+2]*kv[j+2] + kv[j+3]*kv[j+3];
    }
    ssk += __shfl_xor(ssk, 1, 64);
    ssk += __shfl_xor(ssk, 2, 64);
    const float rk = rsqrtf(ssk + 1e-6f);
    const float ekr = __expf(gc[r]) * bet[r];
#pragma unroll
    for (int j = 0; j < 32; ++j) {
      float kn = kv[j] * rk;
      ktb[r * 136 + q4 * 32 + j] = f2bf(kn);
      XtB[(q4 * 32 + j) * 68 + r] = f2bf(kn * ekr);
    }
  }
  __syncthreads();

  float xr[64];

  {
    static const signed char SJ[10][2] = {{0,0},{1,0},{1,1},{2,0},{2,1},{2,2},{3,0},{3,1},{3,2},{3,3}};
    static const signed char SB[5] = {0, 3, 6, 8, 10};
    for (int sj = SB[w]; sj < SB[w + 1]; ++sj) {
      const int mt = SJ[sj][0], nt = SJ[sj][1];
      f32x4v acc = (f32x4v){0.f, 0.f, 0.f, 0.f};
#pragma unroll
      for (int ks = 0; ks < 4; ++ks) {
        bf16x8 af = *(const bf16x8*)&ktb[(mt * 16 + rlo) * 136 + ks * 32 + khi * 8];
        bf16x8 bf_ = *(const bf16x8*)&ktb[(nt * 16 + rlo) * 136 + ks * 32 + khi * 8];
        acc = __builtin_amdgcn_mfma_f32_16x16x32_bf16(af, bf_, acc, 0, 0, 0);
      }
      const int j = nt * 16 + rlo;
#pragma unroll
      for (int r2 = 0; r2 < 4; ++r2) {
        const int i = mt * 16 + khi * 4 + r2;
        if (j < i) Amat[i * 68 + j] = -bet[i] * __expf(gc[i] - gc[j]) * acc[r2];
      }
    }
    if (t < 128) {
      const unsigned short* Xc = XtB + t * 68;
#pragma unroll
      for (int j = 0; j < 64; j += 4) {
        ushort4 xv = *(const ushort4*)(Xc + j);
        xr[j] = bf2f(xv.x); xr[j + 1] = bf2f(xv.y); xr[j + 2] = bf2f(xv.z); xr[j + 3] = bf2f(xv.w);
      }
    }
  }
  __syncthreads();

  {
    const unsigned short* vp = QKV + grow + 4096 + h * 128 + q4 * 32;
    const float brow = bet[r];
#pragma unroll
    for (int j = 0; j < 32; j += 4) {
      ushort4 vm = *(const ushort4*)(vp + j);
      XtB[(q4 * 32 + j + 0) * 68 + r] = f2bf(bf2f(vm.x) * brow);
      XtB[(q4 * 32 + j + 1) * 68 + r] = f2bf(bf2f(vm.y) * brow);
      XtB[(q4 * 32 + j + 2) * 68 + r] = f2bf(bf2f(vm.z) * brow);
      XtB[(q4 * 32 + j + 3) * 68 + r] = f2bf(bf2f(vm.w) * brow);
    }
  }
  __syncthreads();
  if (t >= 128) {
    const unsigned short* Xc = XtB + (t - 128) * 68;
#pragma unroll
    for (int j = 0; j < 64; j += 4) {
      ushort4 xv = *(const ushort4*)(Xc + j);
      xr[j] = bf2f(xv.x); xr[j + 1] = bf2f(xv.y); xr[j + 2] = bf2f(xv.z); xr[j + 3] = bf2f(xv.w);
    }
  }
  __syncthreads();

#pragma unroll
  for (int ib = 0; ib < 8; ++ib) {
    const int i0 = ib * 8;
    float p[8] = {0, 0, 0, 0, 0, 0, 0, 0};
#pragma unroll
    for (int j = 0; j < i0; j += 4) {
#pragma unroll
      for (int r2 = 0; r2 < 8; ++r2) {
        f32x4v ar = *(const f32x4v*)&Amat[(i0 + r2) * 68 + j];
        p[r2] += ar[0] * xr[j] + ar[1] * xr[j + 1] + ar[2] * xr[j + 2] + ar[3] * xr[j + 3];
      }
    }
#pragma unroll
    for (int r2 = 0; r2 < 8; ++r2) {
      float v = xr[i0 + r2] + p[r2];
#pragma unroll
      for (int r3 = 0; r3 < r2; ++r3) v += Amat[(i0 + r2) * 68 + i0 + r3] * xr[i0 + r3];
      xr[i0 + r2] = v;
    }
  }

  if (t < 128) {
    unsigned short* Xc = XtB + t * 68;
#pragma unroll
    for (int j = 0; j < 64; j += 4) {
      ushort4 xv;
      xv.x = f2bf(xr[j]); xv.y = f2bf(xr[j + 1]); xv.z = f2bf(xr[j + 2]); xv.w = f2bf(xr[j + 3]);
      *(ushort4*)(Xc + j) = xv;
    }
  }
  __syncthreads();
  {
    unsigned short* wdst = WU + (rowbase + row0 + r) * (size_t)LDC1 + h * 128 + q4 * 32;
#pragma unroll
    for (int j = 0; j < 32; ++j) wdst[j] = XtB[(q4 * 32 + j) * 68 + r];
  }
  __syncthreads();
  if (t >= 128) {
    unsigned short* Xc = XtB + (t - 128) * 68;
#pragma unroll
    for (int j = 0; j < 64; j += 4) {
      ushort4 xv;
      xv.x = f2bf(xr[j]); xv.y = f2bf(xr[j + 1]); xv.z = f2bf(xr[j + 2]); xv.w = f2bf(xr[j + 3]);
      *(ushort4*)(Xc + j) = xv;
    }
  }
  __syncthreads();
  {
    unsigned short* udst = WU + (rowbase + row0 + r) * (size_t)LDC1 + 4096 + h * 128 + q4 * 32;
#pragma unroll
    for (int j = 0; j < 32; ++j) udst[j] = XtB[(q4 * 32 + j) * 68 + r];
  }
  __syncthreads();

  {
    const unsigned short* qp = QKV + grow + hq * 128 + q4 * 32;
    float qv[32]; float ssq = 0.f;
#pragma unroll
    for (int j = 0; j < 32; j += 4) {
      ushort4 qm = *(const ushort4*)(qp + j);
      qv[j] = bf2f(qm.x); qv[j + 1] = bf2f(qm.y); qv[j + 2] = bf2f(qm.z); qv[j + 3] = bf2f(qm.w);
      ssq += qv[j]*qv[j] + qv[j+1]*qv[j+1] + qv[j+2]*qv[j+2] + qv[j+3]*qv[j+3];
    }
    ssq += __shfl_xor(ssq, 1, 64);
    ssq += __shfl_xor(ssq, 2, 64);
    const float rq = rsqrtf(ssq + 1e-6f) * 0.08838834764831845f;
#pragma unroll
    for (int j = 0; j < 32; ++j) qb[r * 136 + q4 * 32 + j] = f2bf(qv[j] * rq);
  }
  __syncthreads();

  {
    const size_t abase = (((size_t)b * 32 + h) * 32 + cix) * 4096;
    static const signed char CJ[10][2] = {{0,0},{1,0},{1,1},{2,0},{2,1},{2,2},{3,0},{3,1},{3,2},{3,3}};
    static const signed char CB[5] = {0, 3, 6, 8, 10};
    static const signed char ZJ[6][2] = {{0,1},{0,2},{0,3},{1,2},{1,3},{2,3}};
    static const signed char ZB[5] = {0, 0, 0, 3, 6};
#pragma unroll 1
    for (int cj = CB[w]; cj < CB[w + 1]; ++cj) {
      const int bi = CJ[cj][0], nt = CJ[cj][1];
      const int j = nt * 16 + rlo;
      f32x4v acc = (f32x4v){0.f, 0.f, 0.f, 0.f};
#pragma unroll
      for (int ks = 0; ks < 4; ++ks) {
        bf16x8 af = *(const bf16x8*)&qb[(bi * 16 + rlo) * 136 + ks * 32 + khi * 8];
        bf16x8 bf_ = *(const bf16x8*)&ktb[(nt * 16 + rlo) * 136 + ks * 32 + khi * 8];
        acc = __builtin_amdgcn_mfma_f32_16x16x32_bf16(af, bf_, acc, 0, 0, 0);
      }
#pragma unroll
      for (int r2 = 0; r2 < 4; ++r2) {
        const int i = bi * 16 + khi * 4 + r2;
        float v = (j <= i) ? __expf(gc[i] - gc[j]) * acc[r2] : 0.f;
        ATTN[abase + i * 64 + j] = f2bf(v);
      }
    }
#pragma unroll 1
    for (int zj = ZB[w]; zj < ZB[w + 1]; ++zj) {
      const int bi = ZJ[zj][0], nt = ZJ[zj][1];
#pragma unroll
      for (int r2 = 0; r2 < 4; ++r2)
        ATTN[abase + (bi * 16 + khi * 4 + r2) * 64 + nt * 16 + rlo] = 0;
    }
  }
}

// ---------------------------------------------------------------- SEQ: state recurrence
// ktT staged from precomputed KNT via coalesced uint4 copies (no norm, no scatter).
#define SEQ_SMEM 70400
__global__ __launch_bounds__(256) void seq_kernel(const unsigned short* __restrict__ QKV,
                                                  const float* __restrict__ G,
                                                  const unsigned short* __restrict__ WU,
                                                  const unsigned short* __restrict__ ATTN,
                                                  const unsigned short* __restrict__ KNT,
                                                  unsigned short* __restrict__ CORE) {
  extern __shared__ char smem[];
  unsigned short* ktT    = (unsigned short*)smem;            // [128][88]
  unsigned short* wb     = (unsigned short*)(smem + 22528);  // [64][136]
  unsigned short* attnb  = (unsigned short*)(smem + 39936);  // [64][88]
  float* stateT          = (float*)(smem + 51200);           // [16][136]
  unsigned short* stateTb = (unsigned short*)(smem + 59904); // [16][136]
  unsigned short* vnTb   = (unsigned short*)(smem + 64256);  // [16][88]
  unsigned short* vdTb   = (unsigned short*)(smem + 67072);  // [16][88]

  const int t = threadIdx.x;
  const int lane = t & 63, w = t >> 6;
  const int rlo = lane & 15, khi = lane >> 4;
  const int vq = blockIdx.x & 7;
  const int h = (blockIdx.x >> 3) & 31;
  const int b = blockIdx.x >> 8;
  const int hq = h >> 1;
  const size_t rowbase = (size_t)b * SEQ;
  const size_t ahead = ((size_t)b * 32 + h) * 32;
  const size_t knbase = (((size_t)b * 16 + hq) * 32) << 13;

  for (int i = t; i < 16 * 136; i += 256) { stateT[i] = 0.f; stateTb[i] = 0; }
  __syncthreads();

  bf16x8 qf[4];

#pragma unroll 1
  for (int ncb = 0; ncb < 32; ++ncb) {
    const int row0 = ncb * 64;

    float gv = G[(rowbase + row0 + lane) * NUMV + h];
#pragma unroll
    for (int off = 1; off < 64; off <<= 1) {
      float uph = __shfl_up(gv, off, 64);
      if (lane >= off) gv += uph;
    }
    const float gtot = __shfl(gv, 63, 64);

    {
      const int r = t >> 2, q4 = t & 3;
      // ktT stage from KNT: thread covers d = t>>1, i-half = (t&1)*32 (coalesced)
      const unsigned short* ksrc = KNT + knbase + ((size_t)ncb << 13) + (size_t)t * 32;
      unsigned short* kdst = ktT + (t >> 1) * 88 + (t & 1) * 32;
#pragma unroll
      for (int j = 0; j < 4; ++j)
        *(uint4*)(kdst + j * 8) = *(const uint4*)(ksrc + j * 8);
      const unsigned short* wsrc = WU + (rowbase + row0 + r) * (size_t)LDC1 + h * 128 + q4 * 32;
#pragma unroll
      for (int u2 = 0; u2 < 4; ++u2)
        *(uint4*)&wb[r * 136 + q4 * 32 + u2 * 8] = *(const uint4*)(wsrc + u2 * 8);
      const unsigned short* asrc = ATTN + (ahead + ncb) * 4096 + r * 64 + q4 * 16;
      *(uint4*)&attnb[r * 88 + q4 * 16] = *(const uint4*)(asrc);
      *(uint4*)&attnb[r * 88 + q4 * 16 + 8] = *(const uint4*)(asrc + 8);
      const unsigned short* qsrc = QKV + (rowbase + row0 + w * 16 + rlo) * (size_t)LDQ + hq * 128 + khi * 8;
      float qv[32]; float ssq = 0.f;
#pragma unroll
      for (int ks = 0; ks < 4; ++ks) {
        ushort4 qa = *(const ushort4*)(qsrc + ks * 32);
        ushort4 qb2 = *(const ushort4*)(qsrc + ks * 32 + 4);
        qv[ks*8+0] = bf2f(qa.x); qv[ks*8+1] = bf2f(qa.y); qv[ks*8+2] = bf2f(qa.z); qv[ks*8+3] = bf2f(qa.w);
        qv[ks*8+4] = bf2f(qb2.x); qv[ks*8+5] = bf2f(qb2.y); qv[ks*8+6] = bf2f(qb2.z); qv[ks*8+7] = bf2f(qb2.w);
#pragma unroll
        for (int e = 0; e < 8; ++e) ssq += qv[ks*8+e] * qv[ks*8+e];
      }
      ssq += __shfl_xor(ssq, 16, 64);
      ssq += __shfl_xor(ssq, 32, 64);
      const float rq = rsqrtf(ssq + 1e-6f) * 0.08838834764831845f;
#pragma unroll
      for (int ks = 0; ks < 4; ++ks) {
        bf16x8 tv;
#pragma unroll
        for (int e = 0; e < 8; ++e) tv[e] = (short)f2bf(qv[ks*8+e] * rq);
        qf[ks] = tv;
      }
    }
    __syncthreads();

    f32x4v oacc;
    {
      f32x4v pacc = (f32x4v){0.f, 0.f, 0.f, 0.f};
      oacc = (f32x4v){0.f, 0.f, 0.f, 0.f};
#pragma unroll
      for (int ks = 0; ks < 4; ++ks) {
        bf16x8 aw = *(const bf16x8*)&wb[(w * 16 + rlo) * 136 + ks * 32 + khi * 8];
        bf16x8 bs = *(const bf16x8*)&stateTb[rlo * 136 + ks * 32 + khi * 8];
        pacc = __builtin_amdgcn_mfma_f32_16x16x32_bf16(aw, bs, pacc, 0, 0, 0);
        oacc = __builtin_amdgcn_mfma_f32_16x16x32_bf16(qf[ks], bs, oacc, 0, 0, 0);
      }
#pragma unroll
      for (int r2 = 0; r2 < 4; ++r2) {
        const int i = w * 16 + khi * 4 + r2;
        const float gci = __shfl(gv, i, 64);
        float uv = bf2f(WU[(rowbase + row0 + i) * (size_t)LDC1 + 4096 + h * 128 + vq * 16 + rlo]);
        float vn = uv - pacc[r2];
        vnTb[rlo * 88 + i] = f2bf(vn);
        vdTb[rlo * 88 + i] = f2bf(vn * __expf(gtot - gci));
        oacc[r2] *= __expf(gci);
      }
    }
    __syncthreads();

    {
#pragma unroll
      for (int ks = 0; ks < 2; ++ks) {
        bf16x8 aa = *(const bf16x8*)&attnb[(w * 16 + rlo) * 88 + ks * 32 + khi * 8];
        bf16x8 bv = *(const bf16x8*)&vnTb[rlo * 88 + ks * 32 + khi * 8];
        oacc = __builtin_amdgcn_mfma_f32_16x16x32_bf16(aa, bv, oacc, 0, 0, 0);
      }
      const int col = h * 128 + vq * 16 + rlo;
#pragma unroll
      for (int r2 = 0; r2 < 4; ++r2) {
        const int i = w * 16 + khi * 4 + r2;
        CORE[(rowbase + row0 + i) * (size_t)LDCO + col] = f2bf(oacc[r2]);
      }
      const float egl = __expf(gtot);
#pragma unroll
      for (int n2 = 0; n2 < 2; ++n2) {
        const int dt = w * 2 + n2;
        f32x4v sacc = (f32x4v){0.f, 0.f, 0.f, 0.f};
#pragma unroll
        for (int ks = 0; ks < 2; ++ks) {
          bf16x8 ak = *(const bf16x8*)&ktT[(dt * 16 + rlo) * 88 + ks * 32 + khi * 8];
          bf16x8 bv2 = *(const bf16x8*)&vdTb[rlo * 88 + ks * 32 + khi * 8];
          sacc = __builtin_amdgcn_mfma_f32_16x16x32_bf16(ak, bv2, sacc, 0, 0, 0);
        }
#pragma unroll
        for (int r2 = 0; r2 < 4; ++r2) {
          const int d = dt * 16 + khi * 4 + r2;
          float ns = stateT[rlo * 136 + d] * egl + sacc[r2];
          stateT[rlo * 136 + d] = ns;
          stateTb[rlo * 136 + d] = f2bf(ns);
        }
      }
    }
    __syncthreads();
  }
}

// ---------------------------------------------------------------- gate * silu(z) + RMS-norm
__global__ __launch_bounds__(256) void gatenorm_kernel(const unsigned short* __restrict__ CORE,
                                                       const unsigned short* __restrict__ C1,
                                                       const float* __restrict__ norm_w,
                                                       unsigned short* __restrict__ NRM) {
  const int wid = blockIdx.x * 4 + (threadIdx.x >> 6);
  const int lane = threadIdx.x & 63;
  const int row = wid >> 5, h = wid & 31;
  const int c = lane * 2;
  const size_t cidx = (size_t)row * LDCO + h * 128 + c;
  const size_t zidx = (size_t)row * LDC1 + 8192 + h * 128 + c;
  float g0 = bf2f(CORE[cidx]), g1 = bf2f(CORE[cidx + 1]);
  float z0 = bf2f(C1[zidx]), z1 = bf2f(C1[zidx + 1]);
  g0 *= z0 / (1.f + __expf(-z0));
  g1 *= z1 / (1.f + __expf(-z1));
  float ss = g0 * g0 + g1 * g1;
#pragma unroll
  for (int m = 1; m < 64; m <<= 1) ss += __shfl_xor(ss, m, 64);
  const float rr = rsqrtf(ss * (1.f / 128.f) + 1e-6f);
  unsigned int o = ((unsigned int)f2bf(g1 * rr * norm_w[c + 1]) << 16) | (unsigned int)f2bf(g0 * rr * norm_w[c]);
  *(unsigned int*)(NRM + cidx) = o;
}

// ---------------------------------------------------------------------------
extern "C" void kernel_launch(void* const* d_in, const int* in_sizes, int n_in,
                              void* d_out, int out_size, void* d_ws, size_t ws_size,
                              hipStream_t stream) {
  const float* hs      = (const float*)d_in[0];
  const float* W_qkv   = (const float*)d_in[1];
  const float* W_z     = (const float*)d_in[2];
  const float* W_b     = (const float*)d_in[3];
  const float* W_a     = (const float*)d_in[4];
  const float* conv_w  = (const float*)d_in[5];
  const float* dt_bias = (const float*)d_in[6];
  const float* A_log   = (const float*)d_in[7];
  const float* norm_w  = (const float*)d_in[8];
  const float* W_out   = (const float*)d_in[9];
  float* out = (float*)d_out;
  char* ws = (char*)d_ws;

  const size_t OFF_HSB = 0;                                     // hsb[4096][2080]; later ATTN
  const size_t OFF_WT  = OFF_HSB + (size_t)ROWS * LDH * 2;      // WT[12288][2080]; later CORE+KNT
  const size_t OFF_WOT = OFF_WT + (size_t)NWP * LDW * 2;        // WoT[2048][4160]
  const size_t OFF_WBA = OFF_WOT + (size_t)HIDN * LDWO * 2;     // WbaK[2048][64]
  const size_t OFF_C1  = OFF_WBA + (size_t)2048 * 64 * 2;       // C1[4096][12416]
  const size_t OFF_QKV = OFF_C1 + (size_t)ROWS * LDC1 * 2;      // QKV[4096][8256]; later NRM
  const size_t OFF_G   = OFF_QKV + (size_t)ROWS * LDQ * 2;
  const size_t OFF_B   = OFF_G + (size_t)ROWS * NUMV * 4;
  const size_t OFF_KNT = OFF_WT + (size_t)ROWS * LDCO * 2;      // after CORE, inside old WT

  unsigned short* hsb = (unsigned short*)(ws + OFF_HSB);
  unsigned short* WT  = (unsigned short*)(ws + OFF_WT);
  unsigned short* WoT = (unsigned short*)(ws + OFF_WOT);
  unsigned short* Wba = (unsigned short*)(ws + OFF_WBA);
  unsigned short* C1  = (unsigned short*)(ws + OFF_C1);
  unsigned short* QKV = (unsigned short*)(ws + OFF_QKV);
  float* Gb = (float*)(ws + OFF_G);
  float* Bb = (float*)(ws + OFF_B);
  unsigned short* ATTNb = (unsigned short*)(ws + OFF_HSB);
  unsigned short* COREb = (unsigned short*)(ws + OFF_WT);
  unsigned short* KNTb  = (unsigned short*)(ws + OFF_KNT);
  unsigned short* NRMb  = (unsigned short*)(ws + OFF_QKV);

  cast_kernel<<<ROWS, 256, 0, stream>>>(hs, hsb);
  transpose_kernel<<<dim3(8192 / 64, 2048 / 64), 256, 0, stream>>>(W_qkv, WT, 2048, 8192, LDW, 0);
  transpose_kernel<<<dim3(4096 / 64, 2048 / 64), 256, 0, stream>>>(W_z, WT, 2048, 4096, LDW, 8192);
  bacat_kernel<<<2048 * 64 / 256, 256, 0, stream>>>(W_b, W_a, Wba);
  transpose_kernel<<<dim3(2048 / 64, 4096 / 64), 256, 0, stream>>>(W_out, WoT, 4096, 2048, LDWO, 0);

  ba_kernel<<<ROWS / 8, 256, 0, stream>>>(hsb, Wba, dt_bias, A_log, Gb, Bb);

  void (*g1p)(const unsigned short*, const unsigned short*, void*, int, int, int, int, int, int) =
      gemm_r5_kernel<256, 256, 1>;
  void (*g0p)(const unsigned short*, const unsigned short*, void*, int, int, int, int, int, int) =
      gemm_r5_kernel<128, 256, 0>;
  hipFuncSetAttribute((const void*)g1p, hipFuncAttributeMaxDynamicSharedMemorySize, 5 * (256 + 256) * 64);
  hipFuncSetAttribute((const void*)g0p, hipFuncAttributeMaxDynamicSharedMemorySize, 5 * (128 + 256) * 64);

  gemm_r5_kernel<256, 256, 1><<<dim3(NWP / 256, ROWS / 256), 512, 5 * (256 + 256) * 64, stream>>>(
      hsb, WT, C1, ROWS, NWP, HIDN, LDH, LDW, LDC1);
  conv_silu_kernel<<<(ROWS / 8) * 2048 / 256, 256, 0, stream>>>(C1, conv_w, QKV);

  knorm_kernel<<<2 * 16 * 32, 256, 0, stream>>>(QKV, KNTb);

  hipFuncSetAttribute((const void*)intra_kernel, hipFuncAttributeMaxDynamicSharedMemorySize,
                      INTRA_SMEM);
  intra_kernel<<<2048, 256, INTRA_SMEM, stream>>>(QKV, Gb, Bb, C1, ATTNb);

  hipFuncSetAttribute((const void*)seq_kernel, hipFuncAttributeMaxDynamicSharedMemorySize,
                      SEQ_SMEM);
  seq_kernel<<<512, 256, SEQ_SMEM, stream>>>(QKV, Gb, C1, ATTNb, KNTb, COREb);

  gatenorm_kernel<<<ROWS * NUMV / 4, 256, 0, stream>>>(COREb, C1, norm_w, NRMb);
  gemm_r5_kernel<128, 256, 0><<<dim3(2048 / 256, ROWS / 128), 512, 5 * (128 + 256) * 64, stream>>>(
      NRMb, WoT, out, ROWS, 2048, 4096, LDCO, LDWO, 2048);
}

// Round 21
// 672.228 us; speedup vs baseline: 1.0539x; 1.0413x over previous
//
#include <hip/hip_runtime.h>
#include <cstdint>
#include <cstddef>

// ---------------------------------------------------------------------------
// GatedDeltaNet forward, MI355X/gfx950.
// R21 = R20/R18 + seq blockIdx decode swap: vq in HIGH bits (bid>>6) so the
// 8 vq-slice WGs sharing the same (b,h) w/attn/KNT tiles land on the SAME XCD
// (bids differ by 64 = 0 mod 8) -> per-XCD L2 dedupes the 8x shared reads.
// Pure index remap; numerically identical.
// ---------------------------------------------------------------------------

#define ROWS  4096
#define SEQ   2048
#define HIDN  2048
#define NWP   12288     // logical N of GEMM1 (48 tiles)
#define NUMV  32

#define LDH   2080      // hsb row stride (elems)
#define LDW   2080      // WT row stride
#define LDWO  4160      // WoT row stride
#define LDC1  12416     // C1 / WU row stride
#define LDQ   8256      // QKV row stride
#define LDCO  4160      // CORE / NRM row stride

using bf16x8 = __attribute__((ext_vector_type(8))) short;
using f32x4v = __attribute__((ext_vector_type(4))) float;

__device__ __forceinline__ float bf2f(unsigned short u) {
  union { unsigned int i; float f; } x; x.i = ((unsigned int)u) << 16; return x.f;
}
__device__ __forceinline__ unsigned short f2bf(float f) {
  union { float f; unsigned int u; } x; x.f = f;
  unsigned int u = x.u;
  unsigned int r = (u + 0x7FFFu + ((u >> 16) & 1u)) >> 16;  // RNE
  return (unsigned short)r;
}

typedef const __attribute__((address_space(1))) unsigned int GU32;
typedef __attribute__((address_space(3))) unsigned int LU32;
__device__ __forceinline__ void gld_lds16(const void* g, void* l) {
  GU32* gp = (GU32*)(unsigned long long)(uintptr_t)g;
  LU32* lp = (LU32*)(unsigned int)(uintptr_t)l;  // flat-LDS low32 = LDS offset
  __builtin_amdgcn_global_load_lds(gp, lp, 16, 0, 0);
}
template <int N>
__device__ __forceinline__ void waitcnt_vm() {
  asm volatile("s_waitcnt vmcnt(%0)" ::"i"(N) : "memory");
}

// ---------------------------------------------------------------- cast fp32->bf16 (ld-padded)
__global__ __launch_bounds__(256) void cast_kernel(const float* __restrict__ in,
                                                   unsigned short* __restrict__ out) {
  int i = blockIdx.x * 256 + threadIdx.x;   // ROWS * 256
  int row = i >> 8;
  int c8 = (i & 255) * 8;
  float4 v0 = *(const float4*)(in + (size_t)row * 2048 + c8);
  float4 v1 = *(const float4*)(in + (size_t)row * 2048 + c8 + 4);
  unsigned short o[8];
  o[0] = f2bf(v0.x); o[1] = f2bf(v0.y); o[2] = f2bf(v0.z); o[3] = f2bf(v0.w);
  o[4] = f2bf(v1.x); o[5] = f2bf(v1.y); o[6] = f2bf(v1.z); o[7] = f2bf(v1.w);
  *(uint4*)(out + (size_t)row * LDH + c8) = *(const uint4*)o;
}

// ------------------------------------------------- transpose W[K][N] -> WT[roff+N][K] (ld)
__global__ __launch_bounds__(256) void transpose_kernel(const float* __restrict__ W,
                                                        unsigned short* __restrict__ WT,
                                                        int K, int N, int ld, int roff) {
  __shared__ float tile[64][65];
  const int t = threadIdx.x;
  const int kb = blockIdx.y * 64, nb = blockIdx.x * 64;
  const int r = t >> 2, c0 = (t & 3) * 16;
#pragma unroll
  for (int i = 0; i < 16; ++i) {
    int c = c0 + i;
    float v = 0.f;
    if (nb + c < N) v = W[(size_t)(kb + r) * N + nb + c];
    tile[r][c] = v;
  }
  __syncthreads();
  const int bn = t >> 2, seg = (t & 3) * 16;
  if (nb + bn < N) {
    unsigned short tmp[16];
#pragma unroll
    for (int i = 0; i < 16; ++i) tmp[i] = f2bf(tile[seg + i][bn]);
    unsigned short* dst = WT + (size_t)(roff + nb + bn) * ld + kb + seg;
    *(uint4*)dst = *(const uint4*)&tmp[0];
    *(uint4*)(dst + 8) = *(const uint4*)&tmp[8];
  }
}

// ---------------------------------------------------------------- WbaK[k][c] = [W_b | W_a] bf16
__global__ __launch_bounds__(256) void bacat_kernel(const float* __restrict__ Wb,
                                                    const float* __restrict__ Wa,
                                                    unsigned short* __restrict__ WbaK) {
  int idx = blockIdx.x * 256 + threadIdx.x;   // 2048*64
  int k = idx >> 6, c = idx & 63;
  float v = (c < 32) ? Wb[k * 32 + c] : Wa[k * 32 + (c - 32)];
  WbaK[idx] = f2bf(v);
}

// ---------------------------------------------------------------- b/a projections -> beta/g
__global__ __launch_bounds__(256) void ba_kernel(const unsigned short* __restrict__ hsb,
                                                 const unsigned short* __restrict__ WbaK,
                                                 const float* __restrict__ dt_bias,
                                                 const float* __restrict__ A_log,
                                                 float* __restrict__ G, float* __restrict__ BETA) {
  __shared__ unsigned short hsl[8][2048];   // 32 KB
  __shared__ float pacc[4][8][64];          // 8 KB
  const int t = threadIdx.x;
  const int lane = t & 63, w = t >> 6;
  const int row0 = blockIdx.x * 8;
#pragma unroll
  for (int rr = 0; rr < 2; ++rr) {
    const int r = w * 2 + rr;
    const unsigned short* src = hsb + (size_t)(row0 + r) * LDH + lane * 32;
#pragma unroll
    for (int j = 0; j < 8; ++j)
      *(ushort4*)&hsl[r][lane * 32 + j * 4] = *(const ushort4*)(src + j * 4);
  }
  __syncthreads();
  float acc[8] = {0.f, 0.f, 0.f, 0.f, 0.f, 0.f, 0.f, 0.f};
  const int kb0 = w * 512;
#pragma unroll 1
  for (int k = 0; k < 512; k += 4) {
    const unsigned short* wp = WbaK + (size_t)(kb0 + k) * 64 + lane;
    const float w0 = bf2f(wp[0]);
    const float w1 = bf2f(wp[64]);
    const float w2 = bf2f(wp[128]);
    const float w3 = bf2f(wp[192]);
#pragma unroll
    for (int r = 0; r < 8; ++r) {
      ushort4 hv = *(const ushort4*)&hsl[r][kb0 + k];
      acc[r] += bf2f(hv.x) * w0 + bf2f(hv.y) * w1 + bf2f(hv.z) * w2 + bf2f(hv.w) * w3;
    }
  }
#pragma unroll
  for (int r = 0; r < 8; ++r) pacc[w][r][lane] = acc[r];
  __syncthreads();
  const int r = t >> 5, hc = t & 31;
  float bp = pacc[0][r][hc] + pacc[1][r][hc] + pacc[2][r][hc] + pacc[3][r][hc];
  float ap = pacc[0][r][32 + hc] + pacc[1][r][32 + hc] + pacc[2][r][32 + hc] + pacc[3][r][32 + hc];
  const int idx = (row0 + r) * NUMV + hc;
  BETA[idx] = 1.f / (1.f + __expf(-bp));
  float x = ap + dt_bias[hc];
  float sp = (x > 15.f) ? x : log1pf(__expf(x));
  G[idx] = -__expf(A_log[hc]) * sp;
}

// ---------------------------------------------------------------- k-norm precompute -> KNT
__global__ __launch_bounds__(256) void knorm_kernel(const unsigned short* __restrict__ QKV,
                                                    unsigned short* __restrict__ KNT) {
  const int t = threadIdx.x;
  const int chunk = blockIdx.x & 31;
  const int hq = (blockIdx.x >> 5) & 15;
  const int b = blockIdx.x >> 9;
  const int row0 = chunk * 64;
  const int r = t >> 2, q4 = t & 3;
  const size_t grow = ((size_t)b * SEQ + row0 + r) * (size_t)LDQ;
  const unsigned short* kp = QKV + grow + 2048 + hq * 128 + q4 * 32;
  float kv[32]; float ssk = 0.f;
#pragma unroll
  for (int j = 0; j < 32; j += 4) {
    ushort4 km = *(const ushort4*)(kp + j);
    kv[j] = bf2f(km.x); kv[j + 1] = bf2f(km.y); kv[j + 2] = bf2f(km.z); kv[j + 3] = bf2f(km.w);
    ssk += kv[j]*kv[j] + kv[j+1]*kv[j+1] + kv[j+2]*kv[j+2] + kv[j+3]*kv[j+3];
  }
  ssk += __shfl_xor(ssk, 1, 64);
  ssk += __shfl_xor(ssk, 2, 64);
  const float rk = rsqrtf(ssk + 1e-6f);
  unsigned short* kb = KNT + ((((size_t)b * 16 + hq) * 32 + chunk) << 13) + (size_t)(q4 * 32) * 64 + r;
#pragma unroll
  for (int j = 0; j < 32; ++j) kb[(size_t)j * 64] = f2bf(kv[j] * rk);
}

// ---------------------------------------------------------------- ring-5 pair-barrier GEMM
template <int BM, int BN, int OUT_BF16>
__global__ __launch_bounds__(512) void gemm_r5_kernel(const unsigned short* __restrict__ Ag,
                                                      const unsigned short* __restrict__ Bg,
                                                      void* __restrict__ Cg, int M, int N, int K,
                                                      int lda, int ldb, int ldc) {
  constexpr int PM = BM / 2, PN = BN / 4;
  constexpr int MT = PM / 16, NTF = PN / 16;
  constexpr int NA = BM / 128, NB = BN / 128;
  constexpr int LPS = NA + NB;
  constexpr int REG = (BM + BN) * 64;
  extern __shared__ char lds[];
  const int t = threadIdx.x;
  const int lane = t & 63, wid = t >> 6;
  const int wm = wid >> 2, wn = wid & 3;
  const int rlo = lane & 15, khi = lane >> 4;

  const int gx = gridDim.x, nwg = gx * gridDim.y;
  int id = blockIdx.y * gx + blockIdx.x;
  int sid = (id & 7) * (nwg >> 3) + (id >> 3);
  const int m0 = (sid / gx) * BM, n0 = (sid % gx) * BN;

  const int NT = K >> 6;
  const int NPH = NT * 2;

  const int srow = t >> 2;
  const int scs = ((t & 3) * 16) ^ (((t >> 3) & 3) << 4);
  const char* Ap[NA];
  const char* Bp[NB];
#pragma unroll
  for (int i = 0; i < NA; ++i)
    Ap[i] = (const char*)Ag + (size_t)(m0 + i * 128 + srow) * lda * 2 + scs;
#pragma unroll
  for (int i = 0; i < NB; ++i)
    Bp[i] = (const char*)Bg + (size_t)(n0 + i * 128 + srow) * ldb * 2 + scs;
  char* dst = lds + t * 16;

  int offA[MT], offB[NTF];
#pragma unroll
  for (int mi = 0; mi < MT; ++mi) {
    int o = (wm * PM + mi * 16 + rlo) * 64 + khi * 16;
    o ^= ((o >> 7) & 3) << 4;
    offA[mi] = o;
  }
#pragma unroll
  for (int ni = 0; ni < NTF; ++ni) {
    int o = (wn * PN + ni * 16 + rlo) * 64 + khi * 16;
    o ^= ((o >> 7) & 3) << 4;
    offB[ni] = o + BM * 64;
  }

  f32x4v acc[MT][NTF];
#pragma unroll
  for (int mi = 0; mi < MT; ++mi)
#pragma unroll
    for (int ni = 0; ni < NTF; ++ni) acc[mi][ni] = (f32x4v){0.f, 0.f, 0.f, 0.f};

#define STG(PS, R)                                                           \
  do {                                                                       \
    int kts_ = ((PS) >> 1 < NT) ? ((PS) >> 1) : NT - 1;                      \
    size_t co_ = (size_t)kts_ * 128 + (size_t)((PS) & 1) * 64;               \
    char* d_ = dst + (size_t)(R) * REG;                                      \
    _Pragma("unroll") for (int i_ = 0; i_ < NA; ++i_)                        \
        gld_lds16(Ap[i_] + co_, d_ + i_ * 8192);                             \
    _Pragma("unroll") for (int i_ = 0; i_ < NB; ++i_)                        \
        gld_lds16(Bp[i_] + co_, d_ + BM * 64 + i_ * 8192);                   \
  } while (0)

  STG(0, 0); STG(1, 1); STG(2, 2);
  waitcnt_vm<LPS>();
  __builtin_amdgcn_s_barrier();
  __builtin_amdgcn_sched_barrier(0);

  int rA = 0;
#pragma unroll 1
  for (int q = 0; q < NPH / 2; ++q) {
    const int p0 = q * 2;
    int rB = rA + 1; if (rB >= 5) rB -= 5;
    int tA = rA + 3; if (tA >= 5) tA -= 5;
    int tB = rA + 4; if (tB >= 5) tB -= 5;

    {
      const char* rb = lds + (size_t)rA * REG;
      bf16x8 af[MT], bv[NTF];
#pragma unroll
      for (int mi = 0; mi < MT; ++mi) af[mi] = *(const bf16x8*)(rb + offA[mi]);
#pragma unroll
      for (int ni = 0; ni < NTF; ++ni) bv[ni] = *(const bf16x8*)(rb + offB[ni]);
      STG(p0 + 3, tA);
      __builtin_amdgcn_s_setprio(1);
#pragma unroll
      for (int mi = 0; mi < MT; ++mi)
#pragma unroll
        for (int ni = 0; ni < NTF; ++ni)
          acc[mi][ni] = __builtin_amdgcn_mfma_f32_16x16x32_bf16(af[mi], bv[ni], acc[mi][ni], 0, 0, 0);
      __builtin_amdgcn_s_setprio(0);
    }
    {
      const char* rb = lds + (size_t)rB * REG;
      bf16x8 af[MT], bv[NTF];
#pragma unroll
      for (int mi = 0; mi < MT; ++mi) af[mi] = *(const bf16x8*)(rb + offA[mi]);
#pragma unroll
      for (int ni = 0; ni < NTF; ++ni) bv[ni] = *(const bf16x8*)(rb + offB[ni]);
      STG(p0 + 4, tB);
      __builtin_amdgcn_s_setprio(1);
#pragma unroll
      for (int mi = 0; mi < MT; ++mi)
#pragma unroll
        for (int ni = 0; ni < NTF; ++ni)
          acc[mi][ni] = __builtin_amdgcn_mfma_f32_16x16x32_bf16(af[mi], bv[ni], acc[mi][ni], 0, 0, 0);
      __builtin_amdgcn_s_setprio(0);
    }
    waitcnt_vm<LPS>();
    __builtin_amdgcn_s_barrier();
    __builtin_amdgcn_sched_barrier(0);
    rA += 2; if (rA >= 5) rA -= 5;
  }
#undef STG
  waitcnt_vm<0>();

  const int mrb = khi * 4;
#pragma unroll
  for (int mi = 0; mi < MT; ++mi)
#pragma unroll
    for (int ni = 0; ni < NTF; ++ni)
#pragma unroll
      for (int r = 0; r < 4; ++r) {
        int mm = m0 + wm * PM + mi * 16 + mrb + r;
        int nn = n0 + wn * PN + ni * 16 + rlo;
        float v = acc[mi][ni][r];
        if (OUT_BF16) ((unsigned short*)Cg)[(size_t)mm * ldc + nn] = f2bf(v);
        else          ((float*)Cg)[(size_t)mm * ldc + nn] = v;
      }
}

// ---------------------------------------------------------------- causal conv K=4 + SiLU
__global__ __launch_bounds__(256) void conv_silu_kernel(const unsigned short* __restrict__ C1,
                                                        const float* __restrict__ conv_w,
                                                        unsigned short* __restrict__ QKV) {
  int idx = blockIdx.x * 256 + threadIdx.x;       // (ROWS/8) * 2048
  int nb = idx >> 11;
  int c4 = (idx & 2047) << 2;
  int row0 = nb * 8;
  int s0 = row0 & 2047;
  float4 w0 = *(const float4*)(conv_w + (size_t)(c4 + 0) * 4);
  float4 w1 = *(const float4*)(conv_w + (size_t)(c4 + 1) * 4);
  float4 w2 = *(const float4*)(conv_w + (size_t)(c4 + 2) * 4);
  float4 w3 = *(const float4*)(conv_w + (size_t)(c4 + 3) * 4);
  const float* pw0 = (const float*)&w0;
  const float* pw1 = (const float*)&w1;
  const float* pw2 = (const float*)&w2;
  const float* pw3 = (const float*)&w3;
  ushort4 rw[11];
#pragma unroll
  for (int i = 0; i < 11; ++i) {
    if (s0 + i >= 3) rw[i] = *(const ushort4*)(C1 + (size_t)(row0 - 3 + i) * LDC1 + c4);
    else { rw[i].x = 0; rw[i].y = 0; rw[i].z = 0; rw[i].w = 0; }
  }
#pragma unroll
  for (int j = 0; j < 8; ++j) {
    float a0 = 0.f, a1 = 0.f, a2 = 0.f, a3 = 0.f;
#pragma unroll
    for (int jj = 0; jj < 4; ++jj) {
      ushort4 mv = rw[j + jj];
      a0 += bf2f(mv.x) * pw0[jj];
      a1 += bf2f(mv.y) * pw1[jj];
      a2 += bf2f(mv.z) * pw2[jj];
      a3 += bf2f(mv.w) * pw3[jj];
    }
    ushort4 o;
    o.x = f2bf(a0 / (1.f + __expf(-a0)));
    o.y = f2bf(a1 / (1.f + __expf(-a1)));
    o.z = f2bf(a2 / (1.f + __expf(-a2)));
    o.w = f2bf(a3 / (1.f + __expf(-a3)));
    *(ushort4*)(QKV + (size_t)(row0 + j) * LDQ + c4) = o;
  }
}

// ---------------------------------------------------------------- INTRA: per-chunk solve
#define INTRA_SMEM 52736
__global__ __launch_bounds__(256, 3) void intra_kernel(const unsigned short* __restrict__ QKV,
                                                       const float* __restrict__ G,
                                                       const float* __restrict__ BETA,
                                                       unsigned short* __restrict__ WU,
                                                       unsigned short* __restrict__ ATTN) {
  extern __shared__ char smem[];
  unsigned short* ktb = (unsigned short*)smem;        // [64][136] bf16
  float* Amat = (float*)(smem + 17408);               // [64][68] f32
  unsigned short* XtB = (unsigned short*)(smem + 34816);  // [128][68] bf16
  unsigned short* qb = XtB;                           // [64][136] alias (after solves)
  float* gc  = (float*)(smem + 52224);                // [64]
  float* bet = gc + 64;                               // [64]

  const int t = threadIdx.x;
  const int lane = t & 63, w = t >> 6;
  const int rlo = lane & 15, khi = lane >> 4;
  const int cix = blockIdx.x & 31;
  const int h = (blockIdx.x >> 5) & 31;
  const int b = blockIdx.x >> 10;
  const int hq = h >> 1;
  const int row0 = cix * 64;
  const size_t rowbase = (size_t)b * SEQ;

  if (t < 64) {
    float gv = G[(rowbase + row0 + t) * NUMV + h];
    bet[t] = BETA[(rowbase + row0 + t) * NUMV + h];
#pragma unroll
    for (int off = 1; off < 64; off <<= 1) {
      float u = __shfl_up(gv, off, 64);
      if (t >= off) gv += u;
    }
    gc[t] = gv;
  }
  __syncthreads();

  const int r = t >> 2, q4 = t & 3;
  const size_t grow = (rowbase + row0 + r) * (size_t)LDQ;

  {
    const unsigned short* kp = QKV + grow + 2048 + hq * 128 + q4 * 32;
    float kv[32]; float ssk = 0.f;
#pragma unroll
    for (int j = 0; j < 32; j += 4) {
      ushort4 km = *(const ushort4*)(kp + j);
      kv[j] = bf2f(km.x); kv[j + 1] = bf2f(km.y); kv[j + 2] = bf2f(km.z); kv[j + 3] = bf2f(km.w);
      ssk += kv[j]*kv[j] + kv[j+1]*kv[j+1] + kv[j+2]*kv[j+2] + kv[j+3]*kv[j+3];
    }
    ssk += __shfl_xor(ssk, 1, 64);
    ssk += __shfl_xor(ssk, 2, 64);
    const float rk = rsqrtf(ssk + 1e-6f);
    const float ekr = __expf(gc[r]) * bet[r];
#pragma unroll
    for (int j = 0; j < 32; ++j) {
      float kn = kv[j] * rk;
      ktb[r * 136 + q4 * 32 + j] = f2bf(kn);
      XtB[(q4 * 32 + j) * 68 + r] = f2bf(kn * ekr);
    }
  }
  __syncthreads();

  float xr[64];

  {
    static const signed char SJ[10][2] = {{0,0},{1,0},{1,1},{2,0},{2,1},{2,2},{3,0},{3,1},{3,2},{3,3}};
    static const signed char SB[5] = {0, 3, 6, 8, 10};
    for (int sj = SB[w]; sj < SB[w + 1]; ++sj) {
      const int mt = SJ[sj][0], nt = SJ[sj][1];
      f32x4v acc = (f32x4v){0.f, 0.f, 0.f, 0.f};
#pragma unroll
      for (int ks = 0; ks < 4; ++ks) {
        bf16x8 af = *(const bf16x8*)&ktb[(mt * 16 + rlo) * 136 + ks * 32 + khi * 8];
        bf16x8 bf_ = *(const bf16x8*)&ktb[(nt * 16 + rlo) * 136 + ks * 32 + khi * 8];
        acc = __builtin_amdgcn_mfma_f32_16x16x32_bf16(af, bf_, acc, 0, 0, 0);
      }
      const int j = nt * 16 + rlo;
#pragma unroll
      for (int r2 = 0; r2 < 4; ++r2) {
        const int i = mt * 16 + khi * 4 + r2;
        if (j < i) Amat[i * 68 + j] = -bet[i] * __expf(gc[i] - gc[j]) * acc[r2];
      }
    }
    if (t < 128) {
      const unsigned short* Xc = XtB + t * 68;
#pragma unroll
      for (int j = 0; j < 64; j += 4) {
        ushort4 xv = *(const ushort4*)(Xc + j);
        xr[j] = bf2f(xv.x); xr[j + 1] = bf2f(xv.y); xr[j + 2] = bf2f(xv.z); xr[j + 3] = bf2f(xv.w);
      }
    }
  }
  __syncthreads();

  {
    const unsigned short* vp = QKV + grow + 4096 + h * 128 + q4 * 32;
    const float brow = bet[r];
#pragma unroll
    for (int j = 0; j < 32; j += 4) {
      ushort4 vm = *(const ushort4*)(vp + j);
      XtB[(q4 * 32 + j + 0) * 68 + r] = f2bf(bf2f(vm.x) * brow);
      XtB[(q4 * 32 + j + 1) * 68 + r] = f2bf(bf2f(vm.y) * brow);
      XtB[(q4 * 32 + j + 2) * 68 + r] = f2bf(bf2f(vm.z) * brow);
      XtB[(q4 * 32 + j + 3) * 68 + r] = f2bf(bf2f(vm.w) * brow);
    }
  }
  __syncthreads();
  if (t >= 128) {
    const unsigned short* Xc = XtB + (t - 128) * 68;
#pragma unroll
    for (int j = 0; j < 64; j += 4) {
      ushort4 xv = *(const ushort4*)(Xc + j);
      xr[j] = bf2f(xv.x); xr[j + 1] = bf2f(xv.y); xr[j + 2] = bf2f(xv.z); xr[j + 3] = bf2f(xv.w);
    }
  }
  __syncthreads();

#pragma unroll
  for (int ib = 0; ib < 8; ++ib) {
    const int i0 = ib * 8;
    float p[8] = {0, 0, 0, 0, 0, 0, 0, 0};
#pragma unroll
    for (int j = 0; j < i0; j += 4) {
#pragma unroll
      for (int r2 = 0; r2 < 8; ++r2) {
        f32x4v ar = *(const f32x4v*)&Amat[(i0 + r2) * 68 + j];
        p[r2] += ar[0] * xr[j] + ar[1] * xr[j + 1] + ar[2] * xr[j + 2] + ar[3] * xr[j + 3];
      }
    }
#pragma unroll
    for (int r2 = 0; r2 < 8; ++r2) {
      float v = xr[i0 + r2] + p[r2];
#pragma unroll
      for (int r3 = 0; r3 < r2; ++r3) v += Amat[(i0 + r2) * 68 + i0 + r3] * xr[i0 + r3];
      xr[i0 + r2] = v;
    }
  }

  if (t < 128) {
    unsigned short* Xc = XtB + t * 68;
#pragma unroll
    for (int j = 0; j < 64; j += 4) {
      ushort4 xv;
      xv.x = f2bf(xr[j]); xv.y = f2bf(xr[j + 1]); xv.z = f2bf(xr[j + 2]); xv.w = f2bf(xr[j + 3]);
      *(ushort4*)(Xc + j) = xv;
    }
  }
  __syncthreads();
  {
    unsigned short* wdst = WU + (rowbase + row0 + r) * (size_t)LDC1 + h * 128 + q4 * 32;
#pragma unroll
    for (int j = 0; j < 32; ++j) wdst[j] = XtB[(q4 * 32 + j) * 68 + r];
  }
  __syncthreads();
  if (t >= 128) {
    unsigned short* Xc = XtB + (t - 128) * 68;
#pragma unroll
    for (int j = 0; j < 64; j += 4) {
      ushort4 xv;
      xv.x = f2bf(xr[j]); xv.y = f2bf(xr[j + 1]); xv.z = f2bf(xr[j + 2]); xv.w = f2bf(xr[j + 3]);
      *(ushort4*)(Xc + j) = xv;
    }
  }
  __syncthreads();
  {
    unsigned short* udst = WU + (rowbase + row0 + r) * (size_t)LDC1 + 4096 + h * 128 + q4 * 32;
#pragma unroll
    for (int j = 0; j < 32; ++j) udst[j] = XtB[(q4 * 32 + j) * 68 + r];
  }
  __syncthreads();

  {
    const unsigned short* qp = QKV + grow + hq * 128 + q4 * 32;
    float qv[32]; float ssq = 0.f;
#pragma unroll
    for (int j = 0; j < 32; j += 4) {
      ushort4 qm = *(const ushort4*)(qp + j);
      qv[j] = bf2f(qm.x); qv[j + 1] = bf2f(qm.y); qv[j + 2] = bf2f(qm.z); qv[j + 3] = bf2f(qm.w);
      ssq += qv[j]*qv[j] + qv[j+1]*qv[j+1] + qv[j+2]*qv[j+2] + qv[j+3]*qv[j+3];
    }
    ssq += __shfl_xor(ssq, 1, 64);
    ssq += __shfl_xor(ssq, 2, 64);
    const float rq = rsqrtf(ssq + 1e-6f) * 0.08838834764831845f;
#pragma unroll
    for (int j = 0; j < 32; ++j) qb[r * 136 + q4 * 32 + j] = f2bf(qv[j] * rq);
  }
  __syncthreads();

  {
    const size_t abase = (((size_t)b * 32 + h) * 32 + cix) * 4096;
    static const signed char CJ[10][2] = {{0,0},{1,0},{1,1},{2,0},{2,1},{2,2},{3,0},{3,1},{3,2},{3,3}};
    static const signed char CB[5] = {0, 3, 6, 8, 10};
    static const signed char ZJ[6][2] = {{0,1},{0,2},{0,3},{1,2},{1,3},{2,3}};
    static const signed char ZB[5] = {0, 0, 0, 3, 6};
#pragma unroll 1
    for (int cj = CB[w]; cj < CB[w + 1]; ++cj) {
      const int bi = CJ[cj][0], nt = CJ[cj][1];
      const int j = nt * 16 + rlo;
      f32x4v acc = (f32x4v){0.f, 0.f, 0.f, 0.f};
#pragma unroll
      for (int ks = 0; ks < 4; ++ks) {
        bf16x8 af = *(const bf16x8*)&qb[(bi * 16 + rlo) * 136 + ks * 32 + khi * 8];
        bf16x8 bf_ = *(const bf16x8*)&ktb[(nt * 16 + rlo) * 136 + ks * 32 + khi * 8];
        acc = __builtin_amdgcn_mfma_f32_16x16x32_bf16(af, bf_, acc, 0, 0, 0);
      }
#pragma unroll
      for (int r2 = 0; r2 < 4; ++r2) {
        const int i = bi * 16 + khi * 4 + r2;
        float v = (j <= i) ? __expf(gc[i] - gc[j]) * acc[r2] : 0.f;
        ATTN[abase + i * 64 + j] = f2bf(v);
      }
    }
#pragma unroll 1
    for (int zj = ZB[w]; zj < ZB[w + 1]; ++zj) {
      const int bi = ZJ[zj][0], nt = ZJ[zj][1];
#pragma unroll
      for (int r2 = 0; r2 < 4; ++r2)
        ATTN[abase + (bi * 16 + khi * 4 + r2) * 64 + nt * 16 + rlo] = 0;
    }
  }
}

// ---------------------------------------------------------------- SEQ: state recurrence
// R21: vq in HIGH bits of blockIdx (bid>>6) so the 8 vq sharers of one (b,h)
// land on the SAME XCD (bids differ by 64 = 0 mod 8) -> L2 dedupes w/attn/KNT.
#define SEQ_SMEM 70400
__global__ __launch_bounds__(256) void seq_kernel(const unsigned short* __restrict__ QKV,
                                                  const float* __restrict__ G,
                                                  const unsigned short* __restrict__ WU,
                                                  const unsigned short* __restrict__ ATTN,
                                                  const unsigned short* __restrict__ KNT,
                                                  unsigned short* __restrict__ CORE) {
  extern __shared__ char smem[];
  unsigned short* ktT    = (unsigned short*)smem;            // [128][88]
  unsigned short* wb     = (unsigned short*)(smem + 22528);  // [64][136]
  unsigned short* attnb  = (unsigned short*)(smem + 39936);  // [64][88]
  float* stateT          = (float*)(smem + 51200);           // [16][136]
  unsigned short* stateTb = (unsigned short*)(smem + 59904); // [16][136]
  unsigned short* vnTb   = (unsigned short*)(smem + 64256);  // [16][88]
  unsigned short* vdTb   = (unsigned short*)(smem + 67072);  // [16][88]

  const int t = threadIdx.x;
  const int lane = t & 63, w = t >> 6;
  const int rlo = lane & 15, khi = lane >> 4;
  const int vq = blockIdx.x >> 6;          // R21: vq = high bits
  const int h = blockIdx.x & 31;           // R21: h = low bits
  const int b = (blockIdx.x >> 5) & 1;
  const int hq = h >> 1;
  const size_t rowbase = (size_t)b * SEQ;
  const size_t ahead = ((size_t)b * 32 + h) * 32;
  const size_t knbase = (((size_t)b * 16 + hq) * 32) << 13;

  for (int i = t; i < 16 * 136; i += 256) { stateT[i] = 0.f; stateTb[i] = 0; }
  __syncthreads();

  bf16x8 qf[4];

#pragma unroll 1
  for (int ncb = 0; ncb < 32; ++ncb) {
    const int row0 = ncb * 64;

    float gv = G[(rowbase + row0 + lane) * NUMV + h];
#pragma unroll
    for (int off = 1; off < 64; off <<= 1) {
      float uph = __shfl_up(gv, off, 64);
      if (lane >= off) gv += uph;
    }
    const float gtot = __shfl(gv, 63, 64);

    {
      const int r = t >> 2, q4 = t & 3;
      const unsigned short* ksrc = KNT + knbase + ((size_t)ncb << 13) + (size_t)t * 32;
      unsigned short* kdst = ktT + (t >> 1) * 88 + (t & 1) * 32;
#pragma unroll
      for (int j = 0; j < 4; ++j)
        *(uint4*)(kdst + j * 8) = *(const uint4*)(ksrc + j * 8);
      const unsigned short* wsrc = WU + (rowbase + row0 + r) * (size_t)LDC1 + h * 128 + q4 * 32;
#pragma unroll
      for (int u2 = 0; u2 < 4; ++u2)
        *(uint4*)&wb[r * 136 + q4 * 32 + u2 * 8] = *(const uint4*)(wsrc + u2 * 8);
      const unsigned short* asrc = ATTN + (ahead + ncb) * 4096 + r * 64 + q4 * 16;
      *(uint4*)&attnb[r * 88 + q4 * 16] = *(const uint4*)(asrc);
      *(uint4*)&attnb[r * 88 + q4 * 16 + 8] = *(const uint4*)(asrc + 8);
      const unsigned short* qsrc = QKV + (rowbase + row0 + w * 16 + rlo) * (size_t)LDQ + hq * 128 + khi * 8;
      float qv[32]; float ssq = 0.f;
#pragma unroll
      for (int ks = 0; ks < 4; ++ks) {
        ushort4 qa = *(const ushort4*)(qsrc + ks * 32);
        ushort4 qb2 = *(const ushort4*)(qsrc + ks * 32 + 4);
        qv[ks*8+0] = bf2f(qa.x); qv[ks*8+1] = bf2f(qa.y); qv[ks*8+2] = bf2f(qa.z); qv[ks*8+3] = bf2f(qa.w);
        qv[ks*8+4] = bf2f(qb2.x); qv[ks*8+5] = bf2f(qb2.y); qv[ks*8+6] = bf2f(qb2.z); qv[ks*8+7] = bf2f(qb2.w);
#pragma unroll
        for (int e = 0; e < 8; ++e) ssq += qv[ks*8+e] * qv[ks*8+e];
      }
      ssq += __shfl_xor(ssq, 16, 64);
      ssq += __shfl_xor(ssq, 32, 64);
      const float rq = rsqrtf(ssq + 1e-6f) * 0.08838834764831845f;
#pragma unroll
      for (int ks = 0; ks < 4; ++ks) {
        bf16x8 tv;
#pragma unroll
        for (int e = 0; e < 8; ++e) tv[e] = (short)f2bf(qv[ks*8+e] * rq);
        qf[ks] = tv;
      }
    }
    __syncthreads();

    f32x4v oacc;
    {
      f32x4v pacc = (f32x4v){0.f, 0.f, 0.f, 0.f};
      oacc = (f32x4v){0.f, 0.f, 0.f, 0.f};
#pragma unroll
      for (int ks = 0; ks < 4; ++ks) {
        bf16x8 aw = *(const bf16x8*)&wb[(w * 16 + rlo) * 136 + ks * 32 + khi * 8];
        bf16x8 bs = *(const bf16x8*)&stateTb[rlo * 136 + ks * 32 + khi * 8];
        pacc = __builtin_amdgcn_mfma_f32_16x16x32_bf16(aw, bs, pacc, 0, 0, 0);
        oacc = __builtin_amdgcn_mfma_f32_16x16x32_bf16(qf[ks], bs, oacc, 0, 0, 0);
      }
#pragma unroll
      for (int r2 = 0; r2 < 4; ++r2) {
        const int i = w * 16 + khi * 4 + r2;
        const float gci = __shfl(gv, i, 64);
        float uv = bf2f(WU[(rowbase + row0 + i) * (size_t)LDC1 + 4096 + h * 128 + vq * 16 + rlo]);
        float vn = uv - pacc[r2];
        vnTb[rlo * 88 + i] = f2bf(vn);
        vdTb[rlo * 88 + i] = f2bf(vn * __expf(gtot - gci));
        oacc[r2] *= __expf(gci);
      }
    }
    __syncthreads();

    {
#pragma unroll
      for (int ks = 0; ks < 2; ++ks) {
        bf16x8 aa = *(const bf16x8*)&attnb[(w * 16 + rlo) * 88 + ks * 32 + khi * 8];
        bf16x8 bv = *(const bf16x8*)&vnTb[rlo * 88 + ks * 32 + khi * 8];
        oacc = __builtin_amdgcn_mfma_f32_16x16x32_bf16(aa, bv, oacc, 0, 0, 0);
      }
      const int col = h * 128 + vq * 16 + rlo;
#pragma unroll
      for (int r2 = 0; r2 < 4; ++r2) {
        const int i = w * 16 + khi * 4 + r2;
        CORE[(rowbase + row0 + i) * (size_t)LDCO + col] = f2bf(oacc[r2]);
      }
      const float egl = __expf(gtot);
#pragma unroll
      for (int n2 = 0; n2 < 2; ++n2) {
        const int dt = w * 2 + n2;
        f32x4v sacc = (f32x4v){0.f, 0.f, 0.f, 0.f};
#pragma unroll
        for (int ks = 0; ks < 2; ++ks) {
          bf16x8 ak = *(const bf16x8*)&ktT[(dt * 16 + rlo) * 88 + ks * 32 + khi * 8];
          bf16x8 bv2 = *(const bf16x8*)&vdTb[rlo * 88 + ks * 32 + khi * 8];
          sacc = __builtin_amdgcn_mfma_f32_16x16x32_bf16(ak, bv2, sacc, 0, 0, 0);
        }
#pragma unroll
        for (int r2 = 0; r2 < 4; ++r2) {
          const int d = dt * 16 + khi * 4 + r2;
          float ns = stateT[rlo * 136 + d] * egl + sacc[r2];
          stateT[rlo * 136 + d] = ns;
          stateTb[rlo * 136 + d] = f2bf(ns);
        }
      }
    }
    __syncthreads();
  }
}

// ---------------------------------------------------------------- gate * silu(z) + RMS-norm
__global__ __launch_bounds__(256) void gatenorm_kernel(const unsigned short* __restrict__ CORE,
                                                       const unsigned short* __restrict__ C1,
                                                       const float* __restrict__ norm_w,
                                                       unsigned short* __restrict__ NRM) {
  const int wid = blockIdx.x * 4 + (threadIdx.x >> 6);
  const int lane = threadIdx.x & 63;
  const int row = wid >> 5, h = wid & 31;
  const int c = lane * 2;
  const size_t cidx = (size_t)row * LDCO + h * 128 + c;
  const size_t zidx = (size_t)row * LDC1 + 8192 + h * 128 + c;
  float g0 = bf2f(CORE[cidx]), g1 = bf2f(CORE[cidx + 1]);
  float z0 = bf2f(C1[zidx]), z1 = bf2f(C1[zidx + 1]);
  g0 *= z0 / (1.f + __expf(-z0));
  g1 *= z1 / (1.f + __expf(-z1));
  float ss = g0 * g0 + g1 * g1;
#pragma unroll
  for (int m = 1; m < 64; m <<= 1) ss += __shfl_xor(ss, m, 64);
  const float rr = rsqrtf(ss * (1.f / 128.f) + 1e-6f);
  unsigned int o = ((unsigned int)f2bf(g1 * rr * norm_w[c + 1]) << 16) | (unsigned int)f2bf(g0 * rr * norm_w[c]);
  *(unsigned int*)(NRM + cidx) = o;
}

// ---------------------------------------------------------------------------
extern "C" void kernel_launch(void* const* d_in, const int* in_sizes, int n_in,
                              void* d_out, int out_size, void* d_ws, size_t ws_size,
                              hipStream_t stream) {
  const float* hs      = (const float*)d_in[0];
  const float* W_qkv   = (const float*)d_in[1];
  const float* W_z     = (const float*)d_in[2];
  const float* W_b     = (const float*)d_in[3];
  const float* W_a     = (const float*)d_in[4];
  const float* conv_w  = (const float*)d_in[5];
  const float* dt_bias = (const float*)d_in[6];
  const float* A_log   = (const float*)d_in[7];
  const float* norm_w  = (const float*)d_in[8];
  const float* W_out   = (const float*)d_in[9];
  float* out = (float*)d_out;
  char* ws = (char*)d_ws;

  const size_t OFF_HSB = 0;                                     // hsb[4096][2080]; later ATTN
  const size_t OFF_WT  = OFF_HSB + (size_t)ROWS * LDH * 2;      // WT[12288][2080]; later CORE+KNT
  const size_t OFF_WOT = OFF_WT + (size_t)NWP * LDW * 2;        // WoT[2048][4160]
  const size_t OFF_WBA = OFF_WOT + (size_t)HIDN * LDWO * 2;     // WbaK[2048][64]
  const size_t OFF_C1  = OFF_WBA + (size_t)2048 * 64 * 2;       // C1[4096][12416]
  const size_t OFF_QKV = OFF_C1 + (size_t)ROWS * LDC1 * 2;      // QKV[4096][8256]; later NRM
  const size_t OFF_G   = OFF_QKV + (size_t)ROWS * LDQ * 2;
  const size_t OFF_B   = OFF_G + (size_t)ROWS * NUMV * 4;
  const size_t OFF_KNT = OFF_WT + (size_t)ROWS * LDCO * 2;      // after CORE, inside old WT

  unsigned short* hsb = (unsigned short*)(ws + OFF_HSB);
  unsigned short* WT  = (unsigned short*)(ws + OFF_WT);
  unsigned short* WoT = (unsigned short*)(ws + OFF_WOT);
  unsigned short* Wba = (unsigned short*)(ws + OFF_WBA);
  unsigned short* C1  = (unsigned short*)(ws + OFF_C1);
  unsigned short* QKV = (unsigned short*)(ws + OFF_QKV);
  float* Gb = (float*)(ws + OFF_G);
  float* Bb = (float*)(ws + OFF_B);
  unsigned short* ATTNb = (unsigned short*)(ws + OFF_HSB);
  unsigned short* COREb = (unsigned short*)(ws + OFF_WT);
  unsigned short* KNTb  = (unsigned short*)(ws + OFF_KNT);
  unsigned short* NRMb  = (unsigned short*)(ws + OFF_QKV);

  cast_kernel<<<ROWS, 256, 0, stream>>>(hs, hsb);
  transpose_kernel<<<dim3(8192 / 64, 2048 / 64), 256, 0, stream>>>(W_qkv, WT, 2048, 8192, LDW, 0);
  transpose_kernel<<<dim3(4096 / 64, 2048 / 64), 256, 0, stream>>>(W_z, WT, 2048, 4096, LDW, 8192);
  bacat_kernel<<<2048 * 64 / 256, 256, 0, stream>>>(W_b, W_a, Wba);
  transpose_kernel<<<dim3(2048 / 64, 4096 / 64), 256, 0, stream>>>(W_out, WoT, 4096, 2048, LDWO, 0);

  ba_kernel<<<ROWS / 8, 256, 0, stream>>>(hsb, Wba, dt_bias, A_log, Gb, Bb);

  void (*g1p)(const unsigned short*, const unsigned short*, void*, int, int, int, int, int, int) =
      gemm_r5_kernel<256, 256, 1>;
  void (*g0p)(const unsigned short*, const unsigned short*, void*, int, int, int, int, int, int) =
      gemm_r5_kernel<128, 256, 0>;
  hipFuncSetAttribute((const void*)g1p, hipFuncAttributeMaxDynamicSharedMemorySize, 5 * (256 + 256) * 64);
  hipFuncSetAttribute((const void*)g0p, hipFuncAttributeMaxDynamicSharedMemorySize, 5 * (128 + 256) * 64);

  gemm_r5_kernel<256, 256, 1><<<dim3(NWP / 256, ROWS / 256), 512, 5 * (256 + 256) * 64, stream>>>(
      hsb, WT, C1, ROWS, NWP, HIDN, LDH, LDW, LDC1);
  conv_silu_kernel<<<(ROWS / 8) * 2048 / 256, 256, 0, stream>>>(C1, conv_w, QKV);

  knorm_kernel<<<2 * 16 * 32, 256, 0, stream>>>(QKV, KNTb);

  hipFuncSetAttribute((const void*)intra_kernel, hipFuncAttributeMaxDynamicSharedMemorySize,
                      INTRA_SMEM);
  intra_kernel<<<2048, 256, INTRA_SMEM, stream>>>(QKV, Gb, Bb, C1, ATTNb);

  hipFuncSetAttribute((const void*)seq_kernel, hipFuncAttributeMaxDynamicSharedMemorySize,
                      SEQ_SMEM);
  seq_kernel<<<512, 256, SEQ_SMEM, stream>>>(QKV, Gb, C1, ATTNb, KNTb, COREb);

  gatenorm_kernel<<<ROWS * NUMV / 4, 256, 0, stream>>>(COREb, C1, norm_w, NRMb);
  gemm_r5_kernel<128, 256, 0><<<dim3(2048 / 256, ROWS / 128), 512, 5 * (128 + 256) * 64, stream>>>(
      NRMb, WoT, out, ROWS, 2048, 4096, LDCO, LDWO, 2048);
}